// Round 1
// baseline (23394.798 us; speedup 1.0000x reference)
//
#include <hip/hip_runtime.h>
#include <math.h>

#define N 512
#define BATCH 128
#define EPS 1e-8f
#define TPB 256

// map linear index e -> (r,c) in lower triangle (c <= r), row-major packed
__device__ __forceinline__ void tri_map(int e, int* r_out, int* c_out) {
    int rr = (int)((sqrtf(8.0f * (float)e + 1.0f) - 1.0f) * 0.5f);
    while ((((rr + 1) * (rr + 2)) >> 1) <= e) ++rr;
    while (((rr * (rr + 1)) >> 1) > e) --rr;
    *r_out = rr;
    *c_out = e - ((rr * (rr + 1)) >> 1);
}

// L = B^T B + EPS*I   (L[j*N+i] = dot(B[:,j], B[:,i]) + eps*(i==j))
__global__ void compute_L(const float* __restrict__ B, float* __restrict__ L) {
    const int j = blockIdx.y;
    const int i = blockIdx.x * TPB + threadIdx.x;
    __shared__ float bj[N];
    for (int k = threadIdx.x; k < N; k += TPB) bj[k] = B[k * N + j];
    __syncthreads();
    float acc = 0.0f;
    for (int k = 0; k < N; ++k) acc += B[k * N + i] * bj[k];
    if (i == j) acc += EPS;
    L[j * N + i] = acc;
}

// One block per batch item. batch==BATCH is the normalizer logdet(L+I).
// Gathers active-submatrix lower triangle into a global slab, does in-place
// Cholesky keeping only log(pivot) sums (factor column never written back).
__global__ void chol_logdet(const int* __restrict__ x,
                            const float* __restrict__ L,
                            float* __restrict__ slabs,
                            float* __restrict__ logs,
                            int batch0) {
    const int batch = batch0 + blockIdx.x;
    float* A = slabs + (size_t)blockIdx.x * (size_t)(N * N);
    __shared__ int idx[N];
    __shared__ int s_k;
    __shared__ float colj[N];
    const int tid = threadIdx.x;
    const bool zcase = (batch == BATCH);

    if (tid == 0) {
        int k = 0;
        if (zcase) {
            for (int i = 0; i < N; ++i) idx[i] = i;
            k = N;
        } else {
            const int* xb = x + batch * N;
            for (int i = 0; i < N; ++i)
                if (xb[i] != 0) idx[k++] = i;
        }
        s_k = k;
    }
    __syncthreads();
    const int k = s_k;

    // build lower triangle of A (k x k, lda = N), gathered through idx
    const int T0 = (k * (k + 1)) >> 1;
    for (int e = tid; e < T0; e += TPB) {
        int r, c;
        tri_map(e, &r, &c);
        float v = L[idx[r] * N + idx[c]];
        if (zcase && r == c) v += 1.0f;
        A[r * N + c] = v;
    }
    __syncthreads();

    float sumlog = 0.0f;
    for (int j = 0; j < k; ++j) {
        const float piv = A[j * N + j];           // broadcast load
        if (tid == 0) sumlog += logf(piv);
        const float rs = rsqrtf(piv);
        for (int r = j + 1 + tid; r < k; r += TPB)
            colj[r] = A[r * N + j] * rs;
        __syncthreads();
        const int t = k - 1 - j;                   // trailing size
        const int T = (t * (t + 1)) >> 1;
        for (int e = tid; e < T; e += TPB) {
            int r, c;
            tri_map(e, &r, &c);
            const int rr = j + 1 + r;
            const int cc = j + 1 + c;
            A[rr * N + cc] -= colj[rr] * colj[cc];
        }
        __syncthreads();
    }
    if (tid == 0) logs[batch] = sumlog;
}

__global__ void finalize(const float* __restrict__ logs, float* __restrict__ out) {
    const int i = threadIdx.x;
    out[i] = logs[i] - logs[BATCH];
}

extern "C" void kernel_launch(void* const* d_in, const int* in_sizes, int n_in,
                              void* d_out, int out_size, void* d_ws, size_t ws_size,
                              hipStream_t stream) {
    const int* x = (const int*)d_in[0];
    const float* B = (const float*)d_in[1];
    float* out = (float*)d_out;

    char* ws = (char*)d_ws;
    const size_t L_bytes = (size_t)N * N * 4;       // 1 MB
    float* L = (float*)ws;
    float* logs = (float*)(ws + L_bytes);           // 129 floats
    float* slabs = (float*)(ws + L_bytes + 1024);
    const size_t slab_bytes = (size_t)N * N * 4;    // 1 MB per in-flight batch

    size_t head = L_bytes + 1024;
    size_t avail = (ws_size > head) ? (ws_size - head) : 0;
    int chunk = (int)(avail / slab_bytes);
    if (chunk < 1) chunk = 1;
    if (chunk > BATCH + 1) chunk = BATCH + 1;

    compute_L<<<dim3(N / TPB, N), TPB, 0, stream>>>(B, L);

    for (int start = 0; start < BATCH + 1; start += chunk) {
        int nb = BATCH + 1 - start;
        if (nb > chunk) nb = chunk;
        chol_logdet<<<nb, TPB, 0, stream>>>(x, L, slabs, logs, start);
    }

    finalize<<<1, BATCH, 0, stream>>>(logs, out);
}

// Round 2
// 1273.554 us; speedup vs baseline: 18.3697x; 18.3697x over previous
//
#include <hip/hip_runtime.h>
#include <hip/hip_fp16.h>
#include <math.h>

#define N 512
#define BATCH 128
#define EPS 1e-8f
#define TPB 256
#define NB 8
#define NBZ 32
#define KMAX32 240
#define KMAX16 344
#define UB_BYTES 120448   // >= max(tri32 fp32, tri16 fp16, P+Ph) usage

// ---------- helpers ----------

__device__ __forceinline__ void tri_map(int e, int* r_out, int* c_out) {
    int rr = (int)((sqrtf(8.0f * (float)e + 1.0f) - 1.0f) * 0.5f);
    while ((((rr + 1) * (rr + 2)) >> 1) <= e) ++rr;
    while (((rr * (rr + 1)) >> 1) > e) --rr;
    *r_out = rr;
    *c_out = e - ((rr * (rr + 1)) >> 1);
}

typedef _Float16 h2v __attribute__((ext_vector_type(2)));
__device__ __forceinline__ float fdot2f(__half2 a, __half2 b, float c) {
#if __has_builtin(__builtin_amdgcn_fdot2)
    return __builtin_amdgcn_fdot2(__builtin_bit_cast(h2v, a),
                                  __builtin_bit_cast(h2v, b), c, false);
#else
    float2 fa = __half22float2(a), fb = __half22float2(b);
    return fmaf(fa.x, fb.x, fmaf(fa.y, fb.y, c));
#endif
}

// packed-triangle row base. fp16 rows padded so every row starts even (half2-aligned)
template <int MODE>
__device__ __forceinline__ int tribase(int r) {
    if constexpr (MODE == 32) return (r * (r + 1)) >> 1;
    else return ((r * (r + 1)) >> 1) + ((r + 1) >> 1);
}
template <int MODE>
__device__ __forceinline__ float trild(const char* T, int off) {
    if constexpr (MODE == 32) return ((const float*)T)[off];
    else return __half2float(((const __half*)T)[off]);
}
template <int MODE>
__device__ __forceinline__ void trist(char* T, int off, float v) {
    if constexpr (MODE == 32) ((float*)T)[off] = v;
    else ((__half*)T)[off] = __float2half(v);
}

// ---------- L = B^T B + EPS*I ----------
__global__ void compute_L(const float* __restrict__ B, float* __restrict__ L) {
    const int j = blockIdx.y;
    const int i = blockIdx.x * TPB + threadIdx.x;
    __shared__ float bj[N];
    for (int k = threadIdx.x; k < N; k += TPB) bj[k] = B[k * N + j];
    __syncthreads();
    float acc = 0.0f;
    for (int k = 0; k < N; ++k) acc += B[k * N + i] * bj[k];
    if (i == j) acc += EPS;
    L[j * N + i] = acc;
}

// ---------- LDS-resident packed-triangle Cholesky (MODE = 32 or 16) ----------
template <int MODE>
__device__ float ldsChol(char* T, int k, const int* idx, const float* __restrict__ L) {
    const int tid = threadIdx.x;
    // gather L[S,S] lower triangle
    const int TOT = (k * (k + 1)) >> 1;
    for (int e = tid; e < TOT; e += TPB) {
        int r, c;
        tri_map(e, &r, &c);
        trist<MODE>(T, tribase<MODE>(r) + c, L[idx[r] * N + idx[c]]);
    }
    float slog = 0.0f;
    for (int jb = 0; jb < k; jb += NB) {
        const int nbe = (k - jb < NB) ? (k - jb) : NB;
        // ---- factor panel columns jb .. jb+nbe-1 ----
        for (int jj = 0; jj < nbe; ++jj) {
            const int j = jb + jj;
            __syncthreads();                       // prior writes visible
            const int bj = tribase<MODE>(j);
            const float piv = trild<MODE>(T, bj + j);
            if (tid == 0) slog += logf(piv);
            const float rs = rsqrtf(piv);
            for (int r = j + 1 + tid; r < k; r += TPB) {
                const int br = tribase<MODE>(r);
                trist<MODE>(T, br + j, trild<MODE>(T, br + j) * rs);
            }
            __syncthreads();
            if (jj + 1 < nbe) {
                const int cend = jb + nbe - 1;
                for (int r = j + 1 + tid; r < k; r += TPB) {
                    const int br = tribase<MODE>(r);
                    const float prj = trild<MODE>(T, br + j);
                    const int cmax = (cend < r) ? cend : r;
                    for (int c = j + 1; c <= cmax; ++c)
                        trist<MODE>(T, br + c,
                                    trild<MODE>(T, br + c) -
                                        prj * trild<MODE>(T, tribase<MODE>(c) + j));
                }
            }
        }
        __syncthreads();
        // ---- trailing rank-NB update, 2x2 tiles ----
        const int j1 = jb + nbe;
        const int t = k - j1;
        if (t <= 0) continue;                      // only at last panel
        const int tt = (t + 1) >> 1;
        const int TT = (tt * (tt + 1)) >> 1;
        for (int e = tid; e < TT; e += TPB) {
            int R, C;
            tri_map(e, &R, &C);
            const int r0 = j1 + 2 * R, c0 = j1 + 2 * C;
            const int r1 = r0 + 1, c1 = c0 + 1;
            const int br0 = tribase<MODE>(r0), br1 = tribase<MODE>(r1);
            const int bc0 = tribase<MODE>(c0), bc1 = tribase<MODE>(c1);
            float a00 = trild<MODE>(T, br0 + c0), a01 = trild<MODE>(T, br0 + c1);
            float a10 = trild<MODE>(T, br1 + c0), a11 = trild<MODE>(T, br1 + c1);
            float s00 = 0.f, s01 = 0.f, s10 = 0.f, s11 = 0.f;
            if constexpr (MODE == 16) {
                const __half* H = (const __half*)T;
                const __half2* hr0 = (const __half2*)(H + br0 + jb);
                const __half2* hr1 = (const __half2*)(H + br1 + jb);
                const __half2* hc0 = (const __half2*)(H + bc0 + jb);
                const __half2* hc1 = (const __half2*)(H + bc1 + jb);
#pragma unroll
                for (int q = 0; q < NB / 2; ++q) {
                    const __half2 h0 = hr0[q], h1 = hr1[q];
                    const __half2 g0 = hc0[q], g1 = hc1[q];
                    s00 = fdot2f(h0, g0, s00);
                    s01 = fdot2f(h0, g1, s01);
                    s10 = fdot2f(h1, g0, s10);
                    s11 = fdot2f(h1, g1, s11);
                }
            } else {
                const float* F = (const float*)T;
#pragma unroll
                for (int i = 0; i < NB; ++i) {
                    const float pr0 = F[br0 + jb + i], pr1 = F[br1 + jb + i];
                    const float pc0 = F[bc0 + jb + i], pc1 = F[bc1 + jb + i];
                    s00 = fmaf(pr0, pc0, s00);
                    s01 = fmaf(pr0, pc1, s01);
                    s10 = fmaf(pr1, pc0, s10);
                    s11 = fmaf(pr1, pc1, s11);
                }
            }
            trist<MODE>(T, br0 + c0, a00 - s00);
            if (c1 <= r0) trist<MODE>(T, br0 + c1, a01 - s01);
            if (r1 < k) {
                trist<MODE>(T, br1 + c0, a10 - s10);
                trist<MODE>(T, br1 + c1, a11 - s11);
            }
        }
    }
    __syncthreads();
    return slog;
}

// ---------- global-slab blocked Cholesky (zcase k=512 and k>KMAX16 overflow) ----------
__device__ float globalChol(float* __restrict__ A, int k, const int* idx, bool add1,
                            const float* __restrict__ L, char* Ub) {
    float* P = (float*)Ub;                    // [N][33] padded fp32 panel
    __half* Ph = (__half*)(Ub + N * 33 * 4);  // [N][34] padded fp16 mirror
    const int tid = threadIdx.x;
    float slog = 0.0f;
    for (int jb = 0; jb < k; jb += NBZ) {
        const int t = k - jb;
        const int nbe = (t < NBZ) ? t : NBZ;
        const bool first = (jb == 0);
        // load panel (first panel reads L+add1 directly; later panels read A)
        for (int e = tid; e < t * NBZ; e += TPB) {
            const int r = e >> 5, c = e & 31;
            float v = 0.0f;
            if (c < nbe) {
                const int gr = jb + r, gc = jb + c;
                if (first)
                    v = L[idx[gr] * N + idx[gc]] + ((add1 && gr == gc) ? 1.0f : 0.0f);
                else
                    v = A[gr * N + gc];
            }
            P[r * 33 + c] = v;
        }
        __syncthreads();
        // factor panel in LDS
        for (int jj = 0; jj < nbe; ++jj) {
            const float piv = P[jj * 33 + jj];
            if (tid == 0) slog += logf(piv);
            const float rs = rsqrtf(piv);
            for (int r = jj + 1 + tid; r < t; r += TPB) P[r * 33 + jj] *= rs;
            __syncthreads();
            for (int r = jj + 1 + tid; r < t; r += TPB) {
                const float prj = P[r * 33 + jj];
                for (int c = jj + 1; c < nbe; ++c) P[r * 33 + c] -= prj * P[c * 33 + jj];
            }
            __syncthreads();
        }
        // fp16 mirror for the trailing dots
        for (int e = tid; e < t * NBZ; e += TPB) {
            const int r = e >> 5, c = e & 31;
            Ph[r * 34 + c] = __float2half(P[r * 33 + c]);
        }
        __syncthreads();
        // trailing rank-NBZ update, 2x2 tiles, A in global
        const int j1 = jb + nbe;
        const int t2 = k - j1;
        if (t2 > 0) {
            const int tt = (t2 + 1) >> 1;
            const int TT = (tt * (tt + 1)) >> 1;
            for (int e = tid; e < TT; e += TPB) {
                int R, C;
                tri_map(e, &R, &C);
                const int r0 = j1 + 2 * R, c0 = j1 + 2 * C;
                const int r1 = r0 + 1, c1 = c0 + 1;
                float a00, a01, a10, a11;
                if (first) {
                    const int rr1 = (r1 < k) ? r1 : r0;   // clamp: idx[k] undefined
                    const int cc1 = (c1 < k) ? c1 : c0;
                    a00 = L[idx[r0] * N + idx[c0]] + ((add1 && r0 == c0) ? 1.f : 0.f);
                    a01 = L[idx[r0] * N + idx[cc1]] + ((add1 && r0 == c1) ? 1.f : 0.f);
                    a10 = L[idx[rr1] * N + idx[c0]];
                    a11 = L[idx[rr1] * N + idx[cc1]] + ((add1 && r1 == c1) ? 1.f : 0.f);
                } else {
                    a00 = A[r0 * N + c0];
                    a01 = A[r0 * N + c1];
                    a10 = A[r1 * N + c0];
                    a11 = A[r1 * N + c1];
                }
                const __half2* phr0 = (const __half2*)(Ph + (r0 - jb) * 34);
                const __half2* phr1 = (const __half2*)(Ph + (r1 - jb) * 34);
                const __half2* phc0 = (const __half2*)(Ph + (c0 - jb) * 34);
                const __half2* phc1 = (const __half2*)(Ph + (c1 - jb) * 34);
                float s00 = 0.f, s01 = 0.f, s10 = 0.f, s11 = 0.f;
#pragma unroll
                for (int q = 0; q < NBZ / 2; ++q) {
                    const __half2 h0 = phr0[q], h1 = phr1[q];
                    const __half2 g0 = phc0[q], g1 = phc1[q];
                    s00 = fdot2f(h0, g0, s00);
                    s01 = fdot2f(h0, g1, s01);
                    s10 = fdot2f(h1, g0, s10);
                    s11 = fdot2f(h1, g1, s11);
                }
                A[r0 * N + c0] = a00 - s00;
                if (c1 <= r0) A[r0 * N + c1] = a01 - s01;
                if (r1 < k) {
                    A[r1 * N + c0] = a10 - s10;
                    A[r1 * N + c1] = a11 - s11;
                }
            }
        }
        __syncthreads();
    }
    return slog;
}

// ---------- one block per batch item (block BATCH = normalizer logdet(L+I)) ----------
__global__ __launch_bounds__(TPB) void chol_all(const int* __restrict__ x,
                                                const float* __restrict__ L,
                                                float* __restrict__ slab0,
                                                float* __restrict__ slab1,
                                                float* __restrict__ logs) {
    const int b = blockIdx.x;
    const int tid = threadIdx.x;
    const int lane = tid & 63, wv = tid >> 6;
    __shared__ __align__(16) char Ub[UB_BYTES];
    __shared__ int idx[N];
    __shared__ int wcnt[8];

    // build compacted active-index list via ballot scan (zcase: identity)
    const bool zc = (b == BATCH);
    const bool a0 = zc ? true : (x[b * N + tid] != 0);
    const bool a1 = zc ? true : (x[b * N + (N / 2) + tid] != 0);
    {
        const unsigned long long lt = (1ULL << lane) - 1ULL;
        unsigned long long m0 = __ballot(a0);
        unsigned long long m1 = __ballot(a1);
        if (lane == 0) {
            wcnt[wv] = __popcll(m0);
            wcnt[4 + wv] = __popcll(m1);
        }
        __syncthreads();
        int run = 0, off0 = 0, off1 = 0;
        for (int q = 0; q < 8; ++q) {
            if (q == wv) off0 = run;
            if (q == 4 + wv) off1 = run;
            run += wcnt[q];
        }
        const int p0 = __popcll(m0 & lt);
        const int p1 = __popcll(m1 & lt);
        if (a0) idx[off0 + p0] = tid;
        if (a1) idx[off1 + p1] = (N / 2) + tid;
        wcnt[0] = wcnt[0];  // keep
        __syncthreads();
        if (tid == 0) wcnt[0] = run;  // reuse slot 0 to hold k (after use)
        __syncthreads();
    }
    const int k = wcnt[0];

    float slog;
    if (zc || k > KMAX16)
        slog = globalChol(zc ? slab0 : slab1, k, idx, zc, L, Ub);
    else if (k <= KMAX32)
        slog = ldsChol<32>(Ub, k, idx, L);
    else
        slog = ldsChol<16>(Ub, k, idx, L);
    if (tid == 0) logs[b] = slog;
}

__global__ void finalize(const float* __restrict__ logs, float* __restrict__ out) {
    const int i = threadIdx.x;
    out[i] = logs[i] - logs[BATCH];
}

extern "C" void kernel_launch(void* const* d_in, const int* in_sizes, int n_in,
                              void* d_out, int out_size, void* d_ws, size_t ws_size,
                              hipStream_t stream) {
    const int* x = (const int*)d_in[0];
    const float* B = (const float*)d_in[1];
    float* out = (float*)d_out;

    char* ws = (char*)d_ws;
    const size_t L_bytes = (size_t)N * N * 4;  // 1 MB
    float* L = (float*)ws;
    float* logs = (float*)(ws + L_bytes);
    float* slab0 = (float*)(ws + L_bytes + 4096);
    // second slab only if workspace permits (overflow k>KMAX16 is ~1e-13 probability)
    float* slab1 = (ws_size >= L_bytes + 4096 + 2 * L_bytes) ? (slab0 + N * N) : slab0;

    compute_L<<<dim3(N / TPB, N), TPB, 0, stream>>>(B, L);
    chol_all<<<BATCH + 1, TPB, 0, stream>>>(x, L, slab0, slab1, logs);
    finalize<<<1, BATCH, 0, stream>>>(logs, out);
}

// Round 3
// 658.277 us; speedup vs baseline: 35.5394x; 1.9347x over previous
//
#include <hip/hip_runtime.h>
#include <math.h>

#define N 512
#define BATCH 128
#define EPS 1e-8f
#define TPB 512          // 8 waves
#define PW 32            // panel width
#define KP 304           // max padded k for LDS-resident path (mult of 32 >= it)

typedef _Float16 f16;
typedef _Float16 f16x8 __attribute__((ext_vector_type(8)));
typedef float f32x4 __attribute__((ext_vector_type(4)));

// packed fp16 triangle: row r has rup(r+1,8) halves, every row base 16B-aligned
__device__ __forceinline__ int lh_base(int r) {
    const int a = r >> 3, b = r & 7;
    return 8 * (a + 1) * (4 * a + b);   // = 32a(a+1) + 8b(a+1)
}

#define SLAB_HALVES 133120   // lh_base(512)
#define SLAB_BYTES  266240

// arena offsets (bytes)
#define LH_OFF   0
#define LH_BYTES 94848       // lh_base(304)*2
#define P_OFF    94848       // fp32 [KP][36]
#define DF_OFF   138624      // fp32 [32][33]
#define RS_OFF   142848      // fp32 [32]
#define ARENA_SZ 142976
// zcase/fallback carve (Lh lives in global slab instead)
#define PZ_OFF   0           // fp32 [512][36] = 73728
#define DFZ_OFF  73728
#define RSZ_OFF  77952

// ---------- L = B^T B + EPS*I ----------
__global__ void compute_L(const float* __restrict__ B, float* __restrict__ L) {
    const int j = blockIdx.y;
    const int i = blockIdx.x * 256 + threadIdx.x;
    __shared__ float bj[N];
    for (int k = threadIdx.x; k < N; k += 256) bj[k] = B[k * N + j];
    __syncthreads();
    float acc = 0.0f;
    for (int k = 0; k < N; ++k) acc += B[k * N + i] * bj[k];
    if (i == j) acc += EPS;
    L[j * N + i] = acc;
}

// ---------- left-looking blocked Cholesky, returns sum(log(pivots)) on wave 0 ----
template <int GLOB>
__device__ float do_chol(char* arena, f16* lhg, const float* __restrict__ L,
                         const int* idx, int k, int kp, bool add1) {
    const int tid = threadIdx.x;
    const int lane = tid & 63, wv = tid >> 6;
    float* P   = (float*)(arena + (GLOB ? PZ_OFF  : P_OFF));
    float* Df  = (float*)(arena + (GLOB ? DFZ_OFF : DF_OFF));
    float* rsd = (float*)(arena + (GLOB ? RSZ_OFF : RS_OFF));
    f16* Lh = GLOB ? lhg : (f16*)(arena + LH_OFF);

    float slog = 0.0f;
    const int npan = kp / PW;
    for (int p = 0; p < npan; ++p) {
        const int jb = p * PW;
        const int t = kp - jb;
        const int nrt = t >> 4;
        // ---- (a) S = gather(A) - L(:,0:jb)·L(:,0:jb)^T  into P[t][36]
        const int frow = lane & 15;            // frag row-in-tile
        const int koff = (lane >> 4) * 8;      // frag k-chunk
        const int crow = (lane >> 4) * 4;      // acc row base
        const int ccol = lane & 15;            // acc col
        for (int tile = wv; tile < nrt * 2; tile += (TPB / 64)) {
            const int ri = tile >> 1, cj = tile & 1;
            if (ri == 0 && cj == 1) continue;  // strictly-upper tile of diag block
            const int r0 = jb + 16 * ri, c0 = jb + 16 * cj;
            // gather A values (issued early, latency hidden under MFMA loop)
            f32x4 g;
#pragma unroll
            for (int q = 0; q < 4; ++q) {
                const int gr = r0 + crow + q, gc = c0 + ccol;
                float v;
                if (gr < k && gc < k) {
                    v = L[idx[gr] * N + idx[gc]];
                    if (add1 && gr == gc) v += 1.0f;
                } else v = (gr == gc) ? 1.0f : 0.0f;   // identity padding
                g[q] = v;
            }
            const int baseA = lh_base(r0 + frow) + koff;
            const int baseB = lh_base(c0 + frow) + koff;
            f32x4 acc = {0.f, 0.f, 0.f, 0.f};
            for (int kk = 0; kk < jb; kk += 32) {
                const f16x8 af = *(const f16x8*)(&Lh[baseA + kk]);
                const f16x8 bf = *(const f16x8*)(&Lh[baseB + kk]);
                acc = __builtin_amdgcn_mfma_f32_16x16x32_f16(af, bf, acc, 0, 0, 0);
            }
#pragma unroll
            for (int q = 0; q < 4; ++q)
                P[(r0 - jb + crow + q) * 36 + (c0 - jb) + ccol] = g[q] - acc[q];
        }
        __syncthreads();

        // ---- (b) factor 32x32 diag block: wave 0, row-per-lane in registers
        if (wv == 0) {
            const int r = lane & 31;           // lanes 32..63 mirror 0..31
            float row[PW];
#pragma unroll
            for (int c = 0; c < PW; ++c) row[c] = P[r * 36 + c];
            float lslog = 0.0f;
#pragma unroll
            for (int j = 0; j < PW; ++j) {
                const float piv = __shfl(row[j], j);
                const float rs = rsqrtf(piv);
                lslog += logf(piv);
                row[j] *= rs;                   // scale column j (junk for r<j, unused)
                if (lane == 0) rsd[j] = rs;
#pragma unroll
                for (int c = j + 1; c < PW; ++c) {
                    const float lcj = __shfl(row[j], c);   // L[c][j] from lane c
                    row[c] = fmaf(-row[j], lcj, row[c]);
                }
            }
            if (lane < PW) {
#pragma unroll
                for (int c = 0; c < PW; ++c) Df[lane * 33 + c] = row[c];
                const int nb8 = (lane >> 3) + 1;   // chunks covering rup(r+1,8)
#pragma unroll
                for (int q8 = 0; q8 < 4; ++q8) {
                    if (q8 < nb8) {
                        f16x8 hv;
#pragma unroll
                        for (int m = 0; m < 8; ++m) hv[m] = (f16)row[q8 * 8 + m];
                        *(f16x8*)(&Lh[lh_base(jb + lane) + jb + q8 * 8]) = hv;
                    }
                }
            }
            slog += lslog;                      // uniform on wave 0
        }
        __syncthreads();

        // ---- (c) triangular solve: row-per-thread, registers, no barriers
        for (int rl = PW + tid; rl < t; rl += TPB) {
            float s[PW];
#pragma unroll
            for (int c4 = 0; c4 < PW / 4; ++c4) {
                const f32x4 v = *(const f32x4*)(&P[rl * 36 + 4 * c4]);
#pragma unroll
                for (int m = 0; m < 4; ++m) s[4 * c4 + m] = v[m];
            }
#pragma unroll
            for (int c = 0; c < PW; ++c) {
                float v = s[c];
#pragma unroll
                for (int q = 0; q < PW; ++q)
                    if (q < c) v = fmaf(-s[q], Df[c * 33 + q], v);
                s[c] = v * rsd[c];
            }
#pragma unroll
            for (int q8 = 0; q8 < 4; ++q8) {
                f16x8 hv;
#pragma unroll
                for (int m = 0; m < 8; ++m) hv[m] = (f16)s[q8 * 8 + m];
                *(f16x8*)(&Lh[lh_base(jb + rl) + jb + q8 * 8]) = hv;
            }
        }
        __syncthreads();
    }
    return slog;
}

// ---------- one block per batch item; block BATCH = normalizer logdet(L+I) ----
__global__ __launch_bounds__(TPB) void chol_all(const int* __restrict__ x,
                                                const float* __restrict__ L,
                                                f16* __restrict__ slabs, int nslabs,
                                                float* __restrict__ logs) {
    const int b = blockIdx.x;
    const int tid = threadIdx.x;
    const int lane = tid & 63, wv = tid >> 6;
    __shared__ __align__(16) char arena[ARENA_SZ];
    __shared__ int idx[N];
    __shared__ int wcnt[8];

    const bool zc = (b == BATCH);
    const bool act = zc ? true : (x[(size_t)b * N + tid] != 0);
    const unsigned long long m = __ballot(act);
    if (lane == 0) wcnt[wv] = __popcll(m);
    __syncthreads();
    int off = 0, ktot = 0;
    for (int q = 0; q < 8; ++q) {
        if (q < wv) off += wcnt[q];
        ktot += wcnt[q];
    }
    if (act) idx[off + __popcll(m & ((1ULL << lane) - 1ULL))] = tid;
    __syncthreads();

    const int k = ktot;
    const int kp = (k + 31) & ~31;

    float slog;
    if (!zc && kp <= KP) {
        slog = do_chol<0>(arena, nullptr, L, idx, k, kp, false);
    } else {
        int si = zc ? 0 : (nslabs > 1 ? 1 + (b % (nslabs - 1)) : 0);
        slog = do_chol<1>(arena, slabs + (size_t)si * SLAB_HALVES, L, idx, k, kp, zc);
    }
    if (tid == 0) logs[b] = slog;
}

__global__ void finalize(const float* __restrict__ logs, float* __restrict__ out) {
    const int i = threadIdx.x;
    out[i] = logs[i] - logs[BATCH];
}

extern "C" void kernel_launch(void* const* d_in, const int* in_sizes, int n_in,
                              void* d_out, int out_size, void* d_ws, size_t ws_size,
                              hipStream_t stream) {
    const int* x = (const int*)d_in[0];
    const float* B = (const float*)d_in[1];
    float* out = (float*)d_out;

    char* ws = (char*)d_ws;
    const size_t L_bytes = (size_t)N * N * 4;           // 1 MB
    float* L = (float*)ws;
    float* logs = (float*)(ws + L_bytes);
    const size_t slab_off = L_bytes + 4096;
    f16* slabs = (f16*)(ws + slab_off);
    int nslabs = (ws_size > slab_off) ? (int)((ws_size - slab_off) / SLAB_BYTES) : 1;
    if (nslabs < 1) nslabs = 1;
    if (nslabs > 9) nslabs = 9;

    compute_L<<<dim3(N / 256, N), 256, 0, stream>>>(B, L);
    chol_all<<<BATCH + 1, TPB, 0, stream>>>(x, L, slabs, nslabs, logs);
    finalize<<<1, BATCH, 0, stream>>>(logs, out);
}

// Round 4
// 281.172 us; speedup vs baseline: 83.2045x; 2.3412x over previous
//
#include <hip/hip_runtime.h>
#include <math.h>

#define N 512
#define BATCH 128
#define EPS 1e-8f
#define TPB 512          // 8 waves
#define NWV 8
#define PW 16            // panel width
#define KP 304           // max k for LDS-resident factor
#define LN2 0.69314718055994530942f
#define MAX_CT 4         // max (c)-tiles per wave: ceil(31/8)

typedef _Float16 f16;
typedef _Float16 f16x8 __attribute__((ext_vector_type(8)));
typedef float f32x4 __attribute__((ext_vector_type(4)));

// packed fp16 triangle: row r starts 16B-aligned, length rup(r+1,8)
__device__ __forceinline__ int lh_base(int r) {
    const int a = r >> 3, b = r & 7;
    return 8 * (a + 1) * (4 * a + b);
}
#define SLAB_HALVES 133120   // lh_base(512)
#define SLAB_BYTES  266240

// LDS arena offsets (bytes)
#define LH_OFF 0             // fp16 packed triangle, 94848 B (kp<=304)
#define P_OFF  94848         // fp32 [KP][24] = 29184
#define M_OFF  124032        // fp16 [16][40]  = 1280
#define ARENA_SZ 125312
// GLOB carve (Lh lives in global slab)
#define PZ_OFF 0             // fp32 [512][24] = 49152
#define MZ_OFF 49152

// ---------- L = B^T B + EPS*I : 64x64 register-tiled ----------
__global__ __launch_bounds__(256) void compute_L(const float* __restrict__ B,
                                                 float* __restrict__ L) {
    const int r0 = blockIdx.x * 64, c0 = blockIdx.y * 64;
    const int tx = threadIdx.x & 15, ty = threadIdx.x >> 4;
    __shared__ float Bi[16][64];
    __shared__ float Bj[16][64];
    float acc[4][4] = {};
    for (int k0 = 0; k0 < N; k0 += 16) {
#pragma unroll
        for (int q = 0; q < 4; ++q) {
            const int e = threadIdx.x + q * 256;
            const int kr = e >> 6, cc = e & 63;
            Bi[kr][cc] = B[(k0 + kr) * N + r0 + cc];
            Bj[kr][cc] = B[(k0 + kr) * N + c0 + cc];
        }
        __syncthreads();
#pragma unroll
        for (int kq = 0; kq < 16; ++kq) {
            float a[4], b[4];
#pragma unroll
            for (int q = 0; q < 4; ++q) {
                a[q] = Bi[kq][ty * 4 + q];
                b[q] = Bj[kq][tx * 4 + q];
            }
#pragma unroll
            for (int i = 0; i < 4; ++i)
#pragma unroll
                for (int j = 0; j < 4; ++j) acc[i][j] = fmaf(a[i], b[j], acc[i][j]);
        }
        __syncthreads();
    }
#pragma unroll
    for (int i = 0; i < 4; ++i) {
        const int r = r0 + ty * 4 + i;
        f32x4 v;
#pragma unroll
        for (int j = 0; j < 4; ++j) {
            const int c = c0 + tx * 4 + j;
            v[j] = acc[i][j] + ((r == c) ? EPS : 0.0f);
        }
        *(f32x4*)(&L[r * N + c0 + tx * 4]) = v;
    }
}

// ---------- left-looking PW=16 blocked Cholesky ----------
template <int GLOB>
__device__ float do_chol(char* arena, f16* lhg, const float* __restrict__ L,
                         const int* idx, int k, int kp, bool add1) {
    const int tid = threadIdx.x;
    const int lane = tid & 63, wv = tid >> 6;
    f16* Lh = GLOB ? lhg : (f16*)(arena + LH_OFF);
    float* P = (float*)(arena + (GLOB ? PZ_OFF : P_OFF));
    f16* M = (f16*)(arena + (GLOB ? MZ_OFF : M_OFF));

    const int frow = lane & 15;            // MFMA A/B frag row
    const int koff = (lane >> 4) * 8;      // frag k-chunk
    const int crow = (lane >> 4) * 4;      // C-frag row base
    const int ccol = lane & 15;            // C-frag col

    float lg2 = 0.0f;
    const int npan = kp / PW;
    for (int p = 0; p < npan; ++p) {
        const int jb = p * PW;
        const int t = kp - jb;
        const int ntile = t >> 4;

        // ---- (a) S = gather(A) - L(:,0:jb)·L(:,0:jb)^T, panel cols jb..jb+16
        for (int ti = wv; ti < ntile; ti += NWV) {
            const int r0 = jb + 16 * ti;
            f32x4 g;
#pragma unroll
            for (int q = 0; q < 4; ++q) {
                const int gr = r0 + crow + q, gc = jb + ccol;
                float v;
                if (gr < k && gc < k) {
                    v = L[idx[gr] * N + idx[gc]];
                    if (add1 && gr == gc) v += 1.0f;
                } else v = (gr == gc) ? 1.0f : 0.0f;
                g[q] = v;
            }
            const int baseA = lh_base(r0 + frow) + koff;
            const int baseB = lh_base(jb + frow) + koff;
            f32x4 acc = {0.f, 0.f, 0.f, 0.f};
            for (int kk = 0; kk < jb; kk += 32) {
                f16x8 af = {}, bf = {};
                if (kk + koff < jb) {      // half-chunk guard (jb odd mult of 16)
                    af = *(const f16x8*)(&Lh[baseA + kk]);
                    bf = *(const f16x8*)(&Lh[baseB + kk]);
                }
                acc = __builtin_amdgcn_mfma_f32_16x16x32_f16(af, bf, acc, 0, 0, 0);
            }
            const int lr = r0 - jb;
#pragma unroll
            for (int q = 0; q < 4; ++q)
                P[(lr + crow + q) * 24 + ccol] = g[q] - acc[q];
        }
        __syncthreads();

        // ---- prefetch (c) A-frags from P while wave 0 factors
        f16x8 afs[MAX_CT];
#pragma unroll
        for (int it = 0; it < MAX_CT; ++it) {
            f16x8 af = {};
            const int ti = wv + it * NWV;
            if (ti < ntile - 1 && koff < 16) {
                const int lr = 16 * (ti + 1);
                const f32x4 v0 = *(const f32x4*)(&P[(lr + frow) * 24 + koff]);
                const f32x4 v1 = *(const f32x4*)(&P[(lr + frow) * 24 + koff + 4]);
#pragma unroll
                for (int mq = 0; mq < 4; ++mq) {
                    af[mq] = (f16)v0[mq];
                    af[mq + 4] = (f16)v1[mq];
                }
            }
            afs[it] = af;
        }

        // ---- (b) wave 0: factor 16x16 diag, invert, store M + factor rows
        if (wv == 0) {
            const int r = lane & 15;
            float row[PW], rs[PW];
#pragma unroll
            for (int c = 0; c < PW; ++c) row[c] = P[r * 24 + c];
#pragma unroll
            for (int j = 0; j < PW; ++j) {
                const float piv = __shfl(row[j], j);
                lg2 += __log2f(piv);
                const float irs = rsqrtf(piv);
                rs[j] = irs;
                row[j] *= irs;
#pragma unroll
                for (int c = j + 1; c < PW; ++c)
                    row[c] = fmaf(-row[j], __shfl(row[j], c), row[c]);
            }
            // column-per-lane forward substitution: M = T^{-1}
            const int cj = lane & 15;
            float m[PW];
#pragma unroll
            for (int i = 0; i < PW; ++i) {
                float acc = 0.0f;
#pragma unroll
                for (int q = 0; q < PW; ++q)
                    if (q < i) acc = fmaf(__shfl(row[q], i), m[q], acc);
                m[i] = (((cj == i) ? 1.0f : 0.0f) - acc) * rs[i];
            }
            if (lane < 32) {               // lanes 16-31 zero-pad cols 16..31
#pragma unroll
                for (int i = 0; i < PW; ++i)
                    M[i * 40 + lane] = (lane < 16) ? (f16)m[i] : (f16)0.0f;
            }
            if (lane < 16) {               // store factor rows jb..jb+15 to Lh
                const int nb8 = (lane >> 3) + 1;
#pragma unroll
                for (int q8 = 0; q8 < 2; ++q8) {
                    if (q8 < nb8) {
                        f16x8 hv;
#pragma unroll
                        for (int mq = 0; mq < 8; ++mq) hv[mq] = (f16)row[q8 * 8 + mq];
                        *(f16x8*)(&Lh[lh_base(jb + lane) + jb + q8 * 8]) = hv;
                    }
                }
            }
        }
        __syncthreads();

        // ---- (c) X = S_offdiag · M^T : one MFMA per 16-row tile
        const f16x8 bf = *(const f16x8*)(&M[frow * 40 + koff]);
#pragma unroll
        for (int it = 0; it < MAX_CT; ++it) {
            const int ti = wv + it * NWV;
            if (ti < ntile - 1) {
                f32x4 acc = {0.f, 0.f, 0.f, 0.f};
                acc = __builtin_amdgcn_mfma_f32_16x16x32_f16(afs[it], bf, acc, 0, 0, 0);
                const int lr = 16 * (ti + 1);
#pragma unroll
                for (int q = 0; q < 4; ++q)
                    Lh[lh_base(jb + lr + crow + q) + jb + ccol] = (f16)acc[q];
            }
        }
        __syncthreads();
    }
    return lg2 * LN2;
}

// ---------- one block per batch item; block BATCH = logdet(L+I) ----------
__global__ __launch_bounds__(TPB) void chol_all(const int* __restrict__ x,
                                                const float* __restrict__ L,
                                                f16* __restrict__ slabs, int nslabs,
                                                float* __restrict__ logs) {
    const int b = blockIdx.x;
    const int tid = threadIdx.x;
    const int lane = tid & 63, wv = tid >> 6;
    __shared__ __align__(16) char arena[ARENA_SZ];
    __shared__ int idx[N];
    __shared__ int wcnt[8];

    const bool zc = (b == BATCH);
    const bool act = zc ? true : (x[(size_t)b * N + tid] != 0);
    const unsigned long long m = __ballot(act);
    if (lane == 0) wcnt[wv] = __popcll(m);
    __syncthreads();
    int off = 0, ktot = 0;
    for (int q = 0; q < 8; ++q) {
        if (q < wv) off += wcnt[q];
        ktot += wcnt[q];
    }
    if (act) idx[off + __popcll(m & ((1ULL << lane) - 1ULL))] = tid;
    __syncthreads();

    const int k = ktot;
    const int kp = (k + 15) & ~15;

    float slog;
    if (!zc && kp <= KP) {
        slog = do_chol<0>(arena, nullptr, L, idx, k, kp, false);
    } else {
        const int si = zc ? 0 : (nslabs > 1 ? 1 + (b % (nslabs - 1)) : 0);
        slog = do_chol<1>(arena, slabs + (size_t)si * SLAB_HALVES, L, idx, k, kp, zc);
    }
    if (tid == 0) logs[b] = slog;
}

__global__ void finalize(const float* __restrict__ logs, float* __restrict__ out) {
    const int i = threadIdx.x;
    out[i] = logs[i] - logs[BATCH];
}

extern "C" void kernel_launch(void* const* d_in, const int* in_sizes, int n_in,
                              void* d_out, int out_size, void* d_ws, size_t ws_size,
                              hipStream_t stream) {
    const int* x = (const int*)d_in[0];
    const float* B = (const float*)d_in[1];
    float* out = (float*)d_out;

    char* ws = (char*)d_ws;
    const size_t L_bytes = (size_t)N * N * 4;  // 1 MB
    float* L = (float*)ws;
    float* logs = (float*)(ws + L_bytes);
    const size_t slab_off = L_bytes + 4096;
    f16* slabs = (f16*)(ws + slab_off);
    int nslabs = (ws_size > slab_off) ? (int)((ws_size - slab_off) / SLAB_BYTES) : 1;
    if (nslabs < 1) nslabs = 1;
    if (nslabs > 9) nslabs = 9;

    compute_L<<<dim3(8, 8), 256, 0, stream>>>(B, L);
    chol_all<<<BATCH + 1, TPB, 0, stream>>>(x, L, slabs, nslabs, logs);
    finalize<<<1, BATCH, 0, stream>>>(logs, out);
}

// Round 5
// 266.953 us; speedup vs baseline: 87.6365x; 1.0533x over previous
//
#include <hip/hip_runtime.h>
#include <math.h>

#define N 512
#define BATCH 128
#define EPS 1e-8f
#define TPB 512          // 8 waves
#define NWV 8
#define PW 16            // panel width
#define KP 304           // max k for LDS-resident factor
#define LN2 0.69314718055994530942f
#define MAX_CT 4         // max tiles per wave: ceil(32/8)

typedef _Float16 f16;
typedef _Float16 f16x8 __attribute__((ext_vector_type(8)));
typedef float f32x4 __attribute__((ext_vector_type(4)));

// packed fp16 triangle: row r starts 16B-aligned, length rup(r+1,8)
__device__ __forceinline__ int lh_base(int r) {
    const int a = r >> 3, b = r & 7;
    return 8 * (a + 1) * (4 * a + b);
}
#define SLAB_HALVES 133120   // lh_base(512)
#define SLAB_BYTES  266240

// LDS arena offsets (bytes)
#define LH_OFF 0             // fp16 packed triangle, 94848 B (kp<=304)
#define P_OFF  94848         // fp32 [KP][24] = 29184
#define M_OFF  124032        // fp16 [16][40] = 1280
#define ARENA_SZ 125312
// GLOB carve (Lh lives in global slab)
#define PZ_OFF 0             // fp32 [512][24] = 49152
#define MZ_OFF 49152

// cross-lane broadcast via v_readlane (SALU) — lane must be compile-time const
__device__ __forceinline__ float rdl(float v, int l) {
    return __builtin_bit_cast(float,
        __builtin_amdgcn_readlane(__builtin_bit_cast(int, v), l));
}

// ---------- L = B^T B + EPS*I : 64x64 register-tiled ----------
__global__ __launch_bounds__(256) void compute_L(const float* __restrict__ B,
                                                 float* __restrict__ L) {
    const int r0 = blockIdx.x * 64, c0 = blockIdx.y * 64;
    const int tx = threadIdx.x & 15, ty = threadIdx.x >> 4;
    __shared__ float Bi[16][64];
    __shared__ float Bj[16][64];
    float acc[4][4] = {};
    for (int k0 = 0; k0 < N; k0 += 16) {
#pragma unroll
        for (int q = 0; q < 4; ++q) {
            const int e = threadIdx.x + q * 256;
            const int kr = e >> 6, cc = e & 63;
            Bi[kr][cc] = B[(k0 + kr) * N + r0 + cc];
            Bj[kr][cc] = B[(k0 + kr) * N + c0 + cc];
        }
        __syncthreads();
#pragma unroll
        for (int kq = 0; kq < 16; ++kq) {
            float a[4], b[4];
#pragma unroll
            for (int q = 0; q < 4; ++q) {
                a[q] = Bi[kq][ty * 4 + q];
                b[q] = Bj[kq][tx * 4 + q];
            }
#pragma unroll
            for (int i = 0; i < 4; ++i)
#pragma unroll
                for (int j = 0; j < 4; ++j) acc[i][j] = fmaf(a[i], b[j], acc[i][j]);
        }
        __syncthreads();
    }
#pragma unroll
    for (int i = 0; i < 4; ++i) {
        const int r = r0 + ty * 4 + i;
        f32x4 v;
#pragma unroll
        for (int j = 0; j < 4; ++j) {
            const int c = c0 + tx * 4 + j;
            v[j] = acc[i][j] + ((r == c) ? EPS : 0.0f);
        }
        *(f32x4*)(&L[r * N + c0 + tx * 4]) = v;
    }
}

// ---------- left-looking PW=16 blocked Cholesky ----------
template <int GLOB>
__device__ float do_chol(char* arena, f16* lhg, const float* __restrict__ L,
                         const int* idx, int k, int kp, bool add1) {
    const int tid = threadIdx.x;
    const int lane = tid & 63, wv = tid >> 6;
    f16* Lh = GLOB ? lhg : (f16*)(arena + LH_OFF);
    float* P = (float*)(arena + (GLOB ? PZ_OFF : P_OFF));
    f16* M = (f16*)(arena + (GLOB ? MZ_OFF : M_OFF));

    const int frow = lane & 15;            // MFMA A/B frag row
    const int koff = (lane >> 4) * 8;      // frag k-chunk (0,8,16,24)
    const int crow = (lane >> 4) * 4;      // C-frag row base
    const int ccol = lane & 15;            // C-frag col

    float lg2 = 0.0f;
    const int npan = kp / PW;
    for (int p = 0; p < npan; ++p) {
        const int jb = p * PW;
        const int t = kp - jb;
        const int ntile = t >> 4;

        // ---- (a) S = gather(A) - L(:,0:jb)·L(:,0:jb)^T, panel cols jb..jb+15
        // kk-outer / tile-inner: shared B-frag, 4 independent acc chains,
        // 1-deep software prefetch of the next K-chunk.
        {
            f32x4 g[MAX_CT];
            f32x4 acc[MAX_CT];
            int baseA[MAX_CT];
            const int baseB = lh_base(jb + frow) + koff;
#pragma unroll
            for (int it = 0; it < MAX_CT; ++it) {
                const int ti = wv + it * NWV;
                acc[it] = (f32x4){0.f, 0.f, 0.f, 0.f};
                baseA[it] = 0;
                if (ti < ntile) {
                    const int r0 = jb + 16 * ti;
                    baseA[it] = lh_base(r0 + frow) + koff;
#pragma unroll
                    for (int q = 0; q < 4; ++q) {     // scattered gather, issued early
                        const int gr = r0 + crow + q, gc = jb + ccol;
                        float v;
                        if (gr < k && gc < k) {
                            v = L[idx[gr] * N + idx[gc]];
                            if (add1 && gr == gc) v += 1.0f;
                        } else v = (gr == gc) ? 1.0f : 0.0f;
                        g[it][q] = v;
                    }
                }
            }
            const int nkk = (jb + 31) >> 5;
            f16x8 bfc = {};
            f16x8 afc[MAX_CT] = {};
            if (nkk > 0 && koff < jb) {
                bfc = *(const f16x8*)(&Lh[baseB]);
#pragma unroll
                for (int it = 0; it < MAX_CT; ++it)
                    if (wv + it * NWV < ntile)
                        afc[it] = *(const f16x8*)(&Lh[baseA[it]]);
            }
            for (int c = 0; c < nkk; ++c) {
                const int kk2 = (c + 1) << 5;
                f16x8 bfn = {};
                f16x8 afn[MAX_CT] = {};
                if (c + 1 < nkk && kk2 + koff < jb) {
                    bfn = *(const f16x8*)(&Lh[baseB + kk2]);
#pragma unroll
                    for (int it = 0; it < MAX_CT; ++it)
                        if (wv + it * NWV < ntile)
                            afn[it] = *(const f16x8*)(&Lh[baseA[it] + kk2]);
                }
#pragma unroll
                for (int it = 0; it < MAX_CT; ++it)
                    if (wv + it * NWV < ntile)
                        acc[it] = __builtin_amdgcn_mfma_f32_16x16x32_f16(afc[it], bfc,
                                                                         acc[it], 0, 0, 0);
                bfc = bfn;
#pragma unroll
                for (int it = 0; it < MAX_CT; ++it) afc[it] = afn[it];
            }
#pragma unroll
            for (int it = 0; it < MAX_CT; ++it) {
                const int ti = wv + it * NWV;
                if (ti < ntile) {
                    const int lr = 16 * ti;
#pragma unroll
                    for (int q = 0; q < 4; ++q)
                        P[(lr + crow + q) * 24 + ccol] = g[it][q] - acc[it][q];
                }
            }
        }
        __syncthreads();

        // ---- prefetch (c) A-frags from P while wave 0 factors
        f16x8 afs[MAX_CT];
#pragma unroll
        for (int it = 0; it < MAX_CT; ++it) {
            f16x8 af = {};
            const int ti = wv + it * NWV;
            if (ti < ntile - 1 && koff < 16) {
                const int lr = 16 * (ti + 1);
                const f32x4 v0 = *(const f32x4*)(&P[(lr + frow) * 24 + koff]);
                const f32x4 v1 = *(const f32x4*)(&P[(lr + frow) * 24 + koff + 4]);
#pragma unroll
                for (int mq = 0; mq < 4; ++mq) {
                    af[mq] = (f16)v0[mq];
                    af[mq + 4] = (f16)v1[mq];
                }
            }
            afs[it] = af;
        }

        // ---- (b) wave 0: factor 16x16 diag, invert, store M + factor rows
        if (wv == 0) {
            const int r = lane & 15;
            float row[PW], rs[PW];
#pragma unroll
            for (int c = 0; c < PW; ++c) row[c] = P[r * 24 + c];
#pragma unroll
            for (int j = 0; j < PW; ++j) {
                const float piv = rdl(row[j], j);
                lg2 += __log2f(piv);
                const float irs = rsqrtf(piv);
                rs[j] = irs;
                row[j] *= irs;
#pragma unroll
                for (int c = j + 1; c < PW; ++c)
                    row[c] = fmaf(-row[j], rdl(row[j], c), row[c]);
            }
            // column-per-lane forward substitution: M = T^{-1}
            const int cj = lane & 15;
            float m[PW];
#pragma unroll
            for (int i = 0; i < PW; ++i) {
                float acc = 0.0f;
#pragma unroll
                for (int q = 0; q < PW; ++q)
                    if (q < i) acc = fmaf(rdl(row[q], i), m[q], acc);
                m[i] = (((cj == i) ? 1.0f : 0.0f) - acc) * rs[i];
            }
            if (lane < 32) {               // lanes 16-31 zero-pad cols 16..31
#pragma unroll
                for (int i = 0; i < PW; ++i)
                    M[i * 40 + lane] = (lane < 16) ? (f16)m[i] : (f16)0.0f;
            }
            if (lane < 16) {               // store factor rows jb..jb+15 to Lh
                const int nb8 = (lane >> 3) + 1;
#pragma unroll
                for (int q8 = 0; q8 < 2; ++q8) {
                    if (q8 < nb8) {
                        f16x8 hv;
#pragma unroll
                        for (int mq = 0; mq < 8; ++mq) hv[mq] = (f16)row[q8 * 8 + mq];
                        *(f16x8*)(&Lh[lh_base(jb + lane) + jb + q8 * 8]) = hv;
                    }
                }
            }
        }
        __syncthreads();

        // ---- (c) X = S_offdiag · M^T : one MFMA per 16-row tile
        const f16x8 bf = *(const f16x8*)(&M[frow * 40 + koff]);
#pragma unroll
        for (int it = 0; it < MAX_CT; ++it) {
            const int ti = wv + it * NWV;
            if (ti < ntile - 1) {
                f32x4 acc = {0.f, 0.f, 0.f, 0.f};
                acc = __builtin_amdgcn_mfma_f32_16x16x32_f16(afs[it], bf, acc, 0, 0, 0);
                const int lr = 16 * (ti + 1);
#pragma unroll
                for (int q = 0; q < 4; ++q)
                    Lh[lh_base(jb + lr + crow + q) + jb + ccol] = (f16)acc[q];
            }
        }
        __syncthreads();
    }
    return lg2 * LN2;
}

// ---------- one block per batch item; block BATCH = logdet(L+I) ----------
__global__ __launch_bounds__(TPB) void chol_all(const int* __restrict__ x,
                                                const float* __restrict__ L,
                                                f16* __restrict__ slabs, int nslabs,
                                                float* __restrict__ logs) {
    const int b = blockIdx.x;
    const int tid = threadIdx.x;
    const int lane = tid & 63, wv = tid >> 6;
    __shared__ __align__(16) char arena[ARENA_SZ];
    __shared__ int idx[N];
    __shared__ int wcnt[8];

    const bool zc = (b == BATCH);
    const bool act = zc ? true : (x[(size_t)b * N + tid] != 0);
    const unsigned long long m = __ballot(act);
    if (lane == 0) wcnt[wv] = __popcll(m);
    __syncthreads();
    int off = 0, ktot = 0;
    for (int q = 0; q < 8; ++q) {
        if (q < wv) off += wcnt[q];
        ktot += wcnt[q];
    }
    if (act) idx[off + __popcll(m & ((1ULL << lane) - 1ULL))] = tid;
    __syncthreads();

    const int k = ktot;
    const int kp = (k + 15) & ~15;

    float slog;
    if (!zc && kp <= KP) {
        slog = do_chol<0>(arena, nullptr, L, idx, k, kp, false);
    } else {
        const int si = zc ? 0 : (nslabs > 1 ? 1 + (b % (nslabs - 1)) : 0);
        slog = do_chol<1>(arena, slabs + (size_t)si * SLAB_HALVES, L, idx, k, kp, zc);
    }
    if (tid == 0) logs[b] = slog;
}

__global__ void finalize(const float* __restrict__ logs, float* __restrict__ out) {
    const int i = threadIdx.x;
    out[i] = logs[i] - logs[BATCH];
}

extern "C" void kernel_launch(void* const* d_in, const int* in_sizes, int n_in,
                              void* d_out, int out_size, void* d_ws, size_t ws_size,
                              hipStream_t stream) {
    const int* x = (const int*)d_in[0];
    const float* B = (const float*)d_in[1];
    float* out = (float*)d_out;

    char* ws = (char*)d_ws;
    const size_t L_bytes = (size_t)N * N * 4;  // 1 MB
    float* L = (float*)ws;
    float* logs = (float*)(ws + L_bytes);
    const size_t slab_off = L_bytes + 4096;
    f16* slabs = (f16*)(ws + slab_off);
    int nslabs = (ws_size > slab_off) ? (int)((ws_size - slab_off) / SLAB_BYTES) : 1;
    if (nslabs < 1) nslabs = 1;
    if (nslabs > 9) nslabs = 9;

    compute_L<<<dim3(8, 8), 256, 0, stream>>>(B, L);
    chol_all<<<BATCH + 1, TPB, 0, stream>>>(x, L, slabs, nslabs, logs);
    finalize<<<1, BATCH, 0, stream>>>(logs, out);
}

// Round 6
// 265.019 us; speedup vs baseline: 88.2759x; 1.0073x over previous
//
#include <hip/hip_runtime.h>
#include <math.h>

#define N 512
#define BATCH 128
#define EPS 1e-8f
#define TPB 512          // 8 waves
#define KP 304           // max kp for direct LDS path
#define LN2 0.69314718055994530942f
#define SLD 260          // S row stride (floats)

typedef _Float16 f16;
typedef _Float16 f16x8 __attribute__((ext_vector_type(8)));
typedef float f32x4 __attribute__((ext_vector_type(4)));

// packed fp16 triangle: row r starts 16B-aligned, length rup(r+1,8)
__device__ __forceinline__ int lh_base(int r) {
    const int a = r >> 3, b = r & 7;
    return 8 * (a + 1) * (4 * a + b);
}

// LDS arena (bytes): Lh fp16 triangle rows<=304 | P fp32 [512][24] | M fp16 [16][40]
#define LH_OFF 0
#define P_OFF  94848
#define M_OFF  144000
#define ARENA_SZ 145280

// global slab per split-block: G fp16 [256][256] | S fp32 [256][SLD]
#define G_BYTES 131072
#define S_BYTES (256 * SLD * 4)
#define SLAB_BYTES (G_BYTES + S_BYTES)

__device__ __forceinline__ float rdl(float v, int l) {
    return __builtin_bit_cast(float,
        __builtin_amdgcn_readlane(__builtin_bit_cast(int, v), l));
}

__device__ __forceinline__ void tri_map(int e, int* r_out, int* c_out) {
    int rr = (int)((sqrtf(8.0f * (float)e + 1.0f) - 1.0f) * 0.5f);
    while ((((rr + 1) * (rr + 2)) >> 1) <= e) ++rr;
    while (((rr * (rr + 1)) >> 1) > e) --rr;
    *r_out = rr;
    *c_out = e - ((rr * (rr + 1)) >> 1);
}

// ---------- L = B^T B + EPS*I : 64x64 register-tiled ----------
__global__ __launch_bounds__(256) void compute_L(const float* __restrict__ B,
                                                 float* __restrict__ L) {
    const int r0 = blockIdx.x * 64, c0 = blockIdx.y * 64;
    const int tx = threadIdx.x & 15, ty = threadIdx.x >> 4;
    __shared__ float Bi[16][64];
    __shared__ float Bj[16][64];
    float acc[4][4] = {};
    for (int k0 = 0; k0 < N; k0 += 16) {
#pragma unroll
        for (int q = 0; q < 4; ++q) {
            const int e = threadIdx.x + q * 256;
            const int kr = e >> 6, cc = e & 63;
            Bi[kr][cc] = B[(k0 + kr) * N + r0 + cc];
            Bj[kr][cc] = B[(k0 + kr) * N + c0 + cc];
        }
        __syncthreads();
#pragma unroll
        for (int kq = 0; kq < 16; ++kq) {
            float a[4], b[4];
#pragma unroll
            for (int q = 0; q < 4; ++q) {
                a[q] = Bi[kq][ty * 4 + q];
                b[q] = Bj[kq][tx * 4 + q];
            }
#pragma unroll
            for (int i = 0; i < 4; ++i)
#pragma unroll
                for (int j = 0; j < 4; ++j) acc[i][j] = fmaf(a[i], b[j], acc[i][j]);
        }
        __syncthreads();
    }
#pragma unroll
    for (int i = 0; i < 4; ++i) {
        const int r = r0 + ty * 4 + i;
        f32x4 v;
#pragma unroll
        for (int j = 0; j < 4; ++j) {
            const int c = c0 + tx * 4 + j;
            v[j] = acc[i][j] + ((r == c) ? EPS : 0.0f);
        }
        *(f32x4*)(&L[r * N + c0 + tx * 4]) = v;
    }
}

// gather one source entry. MODE 0/1: from L via idx (+add1 diag); MODE 2: from S (lower tri)
template <int MODE>
__device__ __forceinline__ float gath(const float* __restrict__ L,
                                      const float* __restrict__ S, const int* idx,
                                      int k, bool add1, int gr, int gc) {
    if constexpr (MODE <= 1) {
        if (gr < k && gc < k) {
            float v = L[idx[gr] * N + idx[gc]];
            if (add1 && gr == gc) v += 1.0f;
            return v;
        }
        return (gr == gc) ? 1.0f : 0.0f;
    } else {
        if (gr < k && gc < k) {
            const int r2 = gr > gc ? gr : gc, c2 = gr > gc ? gc : gr;
            return S[r2 * SLD + c2];
        }
        return (gr == gc) ? 1.0f : 0.0f;
    }
}

// ---------- left-looking PW=16 panel Cholesky over `ncols` cols, `rows` rows ----------
// MODE 0: direct (all rows in LDS Lh).  MODE 1: split first half (rows>=256 -> G slab).
// MODE 2: split second half (source = S slab). Returns sum(log2(pivots)) on wave 0.
template <int MODE, int CT>
__device__ float chol_panels(char* arena, f16* __restrict__ G, float* __restrict__ S,
                             const float* __restrict__ L, const int* idx,
                             int k, int rows, int ncols, bool add1) {
    const int tid = threadIdx.x;
    const int lane = tid & 63, wv = tid >> 6;
    f16* Lh = (f16*)(arena + LH_OFF);
    float* P = (float*)(arena + P_OFF);
    f16* M = (f16*)(arena + M_OFF);
    const int frow = lane & 15, koff = (lane >> 4) * 8;
    const int crow = (lane >> 4) * 4, ccol = lane & 15;

    float lg2 = 0.0f;
    const int npan = ncols >> 4;
    for (int p = 0; p < npan; ++p) {
        const int jb = p << 4;
        const int ntile = (rows - jb) >> 4;

        // tile ownership: wave 0 -> diag only; wave w>=1 -> tiles w, w+7, w+14, ...
        int r0_[CT], baseA_[CT];
        bool val_[CT], isg_[CT];
#pragma unroll
        for (int it = 0; it < CT; ++it) {
            const int ti = (wv == 0) ? (it == 0 ? 0 : (1 << 20)) : (wv + 7 * it);
            const bool v = ti < ntile;
            const int r0 = jb + ((v ? ti : 0) << 4);
            r0_[it] = r0;
            val_[it] = v;
            const bool gg = (MODE == 1) && v && (r0 >= 256);
            isg_[it] = gg;
            baseA_[it] = gg ? ((r0 - 256 + frow) * 256 + koff)
                            : (lh_base(r0 + frow) + koff);
        }
        const int baseB = lh_base(jb + frow) + koff;

        // scattered gathers (issued early, consumed at P store)
        f32x4 g_[CT];
#pragma unroll
        for (int it = 0; it < CT; ++it)
            if (val_[it]) {
#pragma unroll
                for (int q = 0; q < 4; ++q)
                    g_[it][q] = gath<MODE>(L, S, idx, k, add1, r0_[it] + crow + q, jb + ccol);
            }

        // ---- (a) kk-chain with 2-deep prefetch, shared B-frag
        const int nkk = (jb + 31) >> 5;
        f32x4 acc_[CT];
#pragma unroll
        for (int it = 0; it < CT; ++it) acc_[it] = (f32x4){0.f, 0.f, 0.f, 0.f};

        f16x8 a0[CT], a1[CT], b0, b1;
        auto ldc = [&](int c, f16x8 (&av)[CT], f16x8& bv) {
            const int kk = c << 5;
            const bool ok = (c < nkk) && (kk + koff < jb);
            bv = ok ? *(const f16x8*)(&Lh[baseB + kk]) : (f16x8){};
#pragma unroll
            for (int it = 0; it < CT; ++it) {
                f16x8 vv = {};
                if (ok && val_[it]) {
                    if (MODE == 1 && isg_[it]) vv = *(const f16x8*)(&G[baseA_[it] + kk]);
                    else vv = *(const f16x8*)(&Lh[baseA_[it] + kk]);
                }
                av[it] = vv;
            }
        };
        ldc(0, a0, b0);
        ldc(1, a1, b1);
        for (int c = 0; c < nkk; ++c) {
            f16x8 a2[CT], b2;
            ldc(c + 2, a2, b2);
#pragma unroll
            for (int it = 0; it < CT; ++it)
                if (val_[it])
                    acc_[it] = __builtin_amdgcn_mfma_f32_16x16x32_f16(a0[it], b0, acc_[it], 0, 0, 0);
#pragma unroll
            for (int it = 0; it < CT; ++it) { a0[it] = a1[it]; a1[it] = a2[it]; }
            b0 = b1;
            b1 = b2;
        }

        // P store (own rows) — LDS is in-order per wave, so same-wave re-read is safe
#pragma unroll
        for (int it = 0; it < CT; ++it)
            if (val_[it]) {
                const int lr = r0_[it] - jb;
#pragma unroll
                for (int q = 0; q < 4; ++q)
                    P[(lr + crow + q) * 24 + ccol] = g_[it][q] - acc_[it][q];
            }

        // own (c) A-frags from own P rows (no barrier needed)
        f16x8 afs[CT];
#pragma unroll
        for (int it = 0; it < CT; ++it) {
            f16x8 af = {};
            if (val_[it] && wv != 0 && koff < 16) {
                const int lr = r0_[it] - jb;
                const f32x4 v0 = *(const f32x4*)(&P[(lr + frow) * 24 + koff]);
                const f32x4 v1 = *(const f32x4*)(&P[(lr + frow) * 24 + koff + 4]);
#pragma unroll
                for (int mq = 0; mq < 4; ++mq) {
                    af[mq] = (f16)v0[mq];
                    af[mq + 4] = (f16)v1[mq];
                }
            }
            afs[it] = af;
        }

        // ---- (b) wave 0: factor diag via column ops; inverse as by-product (Gauss-Jordan)
        if (wv == 0) {
            const int r = lane & 15;
            float row[16], w[16];
#pragma unroll
            for (int q4 = 0; q4 < 4; ++q4) {
                const f32x4 t = *(const f32x4*)(&P[r * 24 + 4 * q4]);
#pragma unroll
                for (int m = 0; m < 4; ++m) row[4 * q4 + m] = t[m];
            }
#pragma unroll
            for (int c = 0; c < 16; ++c) w[c] = (c == r) ? 1.0f : 0.0f;
#pragma unroll
            for (int j = 0; j < 16; ++j) {
                const float piv = rdl(row[j], j);
                lg2 += __log2f(piv);
                const float irs = rsqrtf(piv);
                row[j] *= irs;      // col j of L (per-lane)
                w[j] *= irs;        // same col op on W -> W ends as L^{-T}
#pragma unroll
                for (int cc = j + 1; cc < 16; ++cc) {
                    const float s = rdl(row[j], cc);   // L[cc][j], uniform
                    row[cc] = fmaf(-row[j], s, row[cc]);
                    w[cc] = fmaf(-s, w[j], w[cc]);
                }
            }
            if (lane < 16) {        // factor diag rows jb..jb+15 -> Lh (always LDS rows)
                f16x8 hv0, hv1;
#pragma unroll
                for (int m = 0; m < 8; ++m) {
                    hv0[m] = (f16)row[m];
                    hv1[m] = (f16)row[8 + m];
                }
                *(f16x8*)(&Lh[lh_base(jb + lane) + jb]) = hv0;
                if (lane >= 8) *(f16x8*)(&Lh[lh_base(jb + lane) + jb + 8]) = hv1;
            }
            if (lane < 32) {        // M[i][c] = W[c][i] = lane c's w[i]; zero-pad cols 16..31
#pragma unroll
                for (int i = 0; i < 16; ++i)
                    M[i * 40 + lane] = (lane < 16) ? (f16)w[i] : (f16)0.0f;
            }
        }
        __syncthreads();            // barrier 1: M + diag factor rows visible

        // ---- (c) X = S_tile · M^T : one MFMA per owned tile
        const f16x8 bfM = *(const f16x8*)(&M[frow * 40 + koff]);
#pragma unroll
        for (int it = 0; it < CT; ++it) {
            if (val_[it] && wv != 0) {
                f32x4 x = {0.f, 0.f, 0.f, 0.f};
                x = __builtin_amdgcn_mfma_f32_16x16x32_f16(afs[it], bfM, x, 0, 0, 0);
#pragma unroll
                for (int q = 0; q < 4; ++q) {
                    const int gr = r0_[it] + crow + q;
                    const f16 h = (f16)x[q];
                    if (MODE == 1 && gr >= 256) G[(gr - 256) * 256 + jb + ccol] = h;
                    else Lh[lh_base(gr) + jb + ccol] = h;
                }
            }
        }
        __syncthreads();            // barrier 2: factor cols jb..jb+15 published
    }
    return lg2;
}

// ---------- S = A22 - G·G^T (split path), 16x16 tiles over lower triangle ----------
__device__ void schur_gemm(const f16* __restrict__ G, float* __restrict__ S,
                           const float* __restrict__ L, const int* idx,
                           int k, int k2p, bool add1) {
    const int tid = threadIdx.x;
    const int lane = tid & 63, wv = tid >> 6;
    const int frow = lane & 15, koff = (lane >> 4) * 8;
    const int crow = (lane >> 4) * 4, ccol = lane & 15;
    const int nt2 = k2p >> 4, TT = (nt2 * (nt2 + 1)) >> 1;
    for (int e = wv; e < TT; e += 8) {
        int R, C;
        tri_map(e, &R, &C);
        const int r0 = R << 4, c0 = C << 4;
        f32x4 g;
#pragma unroll
        for (int q = 0; q < 4; ++q) {
            const int gr = 256 + r0 + crow + q, gc = 256 + c0 + ccol;
            float v;
            if (gr < k && gc < k) {
                v = L[idx[gr] * N + idx[gc]];
                if (add1 && gr == gc) v += 1.0f;
            } else v = (gr == gc) ? 1.0f : 0.0f;
            g[q] = v;
        }
        const int ba = (r0 + frow) * 256 + koff, bb = (c0 + frow) * 256 + koff;
        f32x4 acc = {0.f, 0.f, 0.f, 0.f};
        f16x8 A0 = *(const f16x8*)(&G[ba]), B0 = *(const f16x8*)(&G[bb]);
        f16x8 A1 = *(const f16x8*)(&G[ba + 32]), B1 = *(const f16x8*)(&G[bb + 32]);
        for (int c = 0; c < 8; ++c) {
            f16x8 A2 = {}, B2 = {};
            if (c + 2 < 8) {
                A2 = *(const f16x8*)(&G[ba + ((c + 2) << 5)]);
                B2 = *(const f16x8*)(&G[bb + ((c + 2) << 5)]);
            }
            acc = __builtin_amdgcn_mfma_f32_16x16x32_f16(A0, B0, acc, 0, 0, 0);
            A0 = A1; B0 = B1; A1 = A2; B1 = B2;
        }
#pragma unroll
        for (int q = 0; q < 4; ++q)
            S[(r0 + crow + q) * SLD + c0 + ccol] = g[q] - acc[q];
    }
}

// ---------- one block per batch item; block BATCH = logdet(L+I) ----------
__global__ __launch_bounds__(TPB) void chol_all(const int* __restrict__ x,
                                                const float* __restrict__ L,
                                                char* __restrict__ slabs, int nslabs,
                                                float* __restrict__ logs) {
    const int b = blockIdx.x;
    const int tid = threadIdx.x;
    const int lane = tid & 63, wv = tid >> 6;
    __shared__ __align__(16) char arena[ARENA_SZ];
    __shared__ int idx[N];
    __shared__ int wcnt[8];

    const bool zc = (b == BATCH);
    const bool act = zc ? true : (x[(size_t)b * N + tid] != 0);
    const unsigned long long m = __ballot(act);
    if (lane == 0) wcnt[wv] = __popcll(m);
    __syncthreads();
    int off = 0, ktot = 0;
    for (int q = 0; q < 8; ++q) {
        if (q < wv) off += wcnt[q];
        ktot += wcnt[q];
    }
    if (act) idx[off + __popcll(m & ((1ULL << lane) - 1ULL))] = tid;
    __syncthreads();

    const int k = ktot;
    const int kp = (k + 15) & ~15;

    float lg2;
    if (!zc && kp <= KP) {
        lg2 = chol_panels<0, 3>(arena, nullptr, nullptr, L, idx, k, kp, kp, false);
    } else {
        const int si = zc ? 0 : (nslabs > 1 ? 1 + (b % (nslabs - 1)) : 0);
        char* slab = slabs + (size_t)si * SLAB_BYTES;
        f16* G = (f16*)slab;
        float* S = (float*)(slab + G_BYTES);
        const int k2 = k - 256, k2p = kp - 256;
        lg2 = chol_panels<1, 5>(arena, G, nullptr, L, idx, k, kp, 256, zc);
        schur_gemm(G, S, L, idx, k, k2p, zc);
        __syncthreads();
        lg2 += chol_panels<2, 3>(arena, nullptr, S, L, idx, k2, k2p, k2p, false);
    }
    if (tid == 0) logs[b] = lg2 * LN2;
}

__global__ void finalize(const float* __restrict__ logs, float* __restrict__ out) {
    const int i = threadIdx.x;
    out[i] = logs[i] - logs[BATCH];
}

extern "C" void kernel_launch(void* const* d_in, const int* in_sizes, int n_in,
                              void* d_out, int out_size, void* d_ws, size_t ws_size,
                              hipStream_t stream) {
    const int* x = (const int*)d_in[0];
    const float* B = (const float*)d_in[1];
    float* out = (float*)d_out;

    char* ws = (char*)d_ws;
    const size_t L_bytes = (size_t)N * N * 4;  // 1 MB
    float* L = (float*)ws;
    float* logs = (float*)(ws + L_bytes);
    const size_t head = L_bytes + 4096;
    char* slabs = ws + head;
    int nslabs = (ws_size > head) ? (int)((ws_size - head) / SLAB_BYTES) : 1;
    if (nslabs < 1) nslabs = 1;
    if (nslabs > 9) nslabs = 9;

    compute_L<<<dim3(8, 8), 256, 0, stream>>>(B, L);
    chol_all<<<BATCH + 1, TPB, 0, stream>>>(x, L, slabs, nslabs, logs);
    finalize<<<1, BATCH, 0, stream>>>(logs, out);
}

// Round 7
// 224.944 us; speedup vs baseline: 104.0029x; 1.1782x over previous
//
#include <hip/hip_runtime.h>
#include <math.h>

#define N 512
#define BATCH 128
#define EPS 1e-8f
#define TPB 1024         // 16 waves, 4/SIMD
#define NW 16
#define KP 304           // max kp for direct LDS path
#define LN2 0.69314718055994530942f
#define SLD 260          // S row stride (floats)

typedef _Float16 f16;
typedef _Float16 f16x8 __attribute__((ext_vector_type(8)));
typedef float f32x4 __attribute__((ext_vector_type(4)));

// packed fp16 triangle: row r starts 16B-aligned, length rup(r+1,8)
__device__ __forceinline__ int lh_base(int r) {
    const int a = r >> 3, b = r & 7;
    return 8 * (a + 1) * (4 * a + b);
}

// LDS arena (bytes): Lh fp16 triangle rows<=304 | P fp32 [512][24] | M fp16 [16][40]
#define LH_OFF 0
#define P_OFF  94848
#define M_OFF  144000
#define ARENA_SZ 145280

// global slab per split-block: G fp16 [256][256] | S fp32 [256][SLD]
#define G_BYTES 131072
#define S_BYTES (256 * SLD * 4)
#define SLAB_BYTES (G_BYTES + S_BYTES)

__device__ __forceinline__ float rdl(float v, int l) {
    return __builtin_bit_cast(float,
        __builtin_amdgcn_readlane(__builtin_bit_cast(int, v), l));
}

__device__ __forceinline__ void tri_map(int e, int* r_out, int* c_out) {
    int rr = (int)((sqrtf(8.0f * (float)e + 1.0f) - 1.0f) * 0.5f);
    while ((((rr + 1) * (rr + 2)) >> 1) <= e) ++rr;
    while (((rr * (rr + 1)) >> 1) > e) --rr;
    *r_out = rr;
    *c_out = e - ((rr * (rr + 1)) >> 1);
}

// ---------- L = B^T B + EPS*I : 64x64 register-tiled ----------
__global__ __launch_bounds__(256) void compute_L(const float* __restrict__ B,
                                                 float* __restrict__ L) {
    const int r0 = blockIdx.x * 64, c0 = blockIdx.y * 64;
    const int tx = threadIdx.x & 15, ty = threadIdx.x >> 4;
    __shared__ float Bi[16][64];
    __shared__ float Bj[16][64];
    float acc[4][4] = {};
    for (int k0 = 0; k0 < N; k0 += 16) {
#pragma unroll
        for (int q = 0; q < 4; ++q) {
            const int e = threadIdx.x + q * 256;
            const int kr = e >> 6, cc = e & 63;
            Bi[kr][cc] = B[(k0 + kr) * N + r0 + cc];
            Bj[kr][cc] = B[(k0 + kr) * N + c0 + cc];
        }
        __syncthreads();
#pragma unroll
        for (int kq = 0; kq < 16; ++kq) {
            float a[4], b[4];
#pragma unroll
            for (int q = 0; q < 4; ++q) {
                a[q] = Bi[kq][ty * 4 + q];
                b[q] = Bj[kq][tx * 4 + q];
            }
#pragma unroll
            for (int i = 0; i < 4; ++i)
#pragma unroll
                for (int j = 0; j < 4; ++j) acc[i][j] = fmaf(a[i], b[j], acc[i][j]);
        }
        __syncthreads();
    }
#pragma unroll
    for (int i = 0; i < 4; ++i) {
        const int r = r0 + ty * 4 + i;
        f32x4 v;
#pragma unroll
        for (int j = 0; j < 4; ++j) {
            const int c = c0 + tx * 4 + j;
            v[j] = acc[i][j] + ((r == c) ? EPS : 0.0f);
        }
        *(f32x4*)(&L[r * N + c0 + tx * 4]) = v;
    }
}

// gather one source entry. MODE 0/1: from L via idx (+add1 diag); MODE 2: from S (lower tri)
template <int MODE>
__device__ __forceinline__ float gath(const float* __restrict__ L,
                                      const float* __restrict__ S, const int* idx,
                                      int k, bool add1, int gr, int gc) {
    if constexpr (MODE <= 1) {
        if (gr < k && gc < k) {
            float v = L[idx[gr] * N + idx[gc]];
            if (add1 && gr == gc) v += 1.0f;
            return v;
        }
        return (gr == gc) ? 1.0f : 0.0f;
    } else {
        if (gr < k && gc < k) {
            const int r2 = gr > gc ? gr : gc, c2 = gr > gc ? gc : gr;
            return S[r2 * SLD + c2];
        }
        return (gr == gc) ? 1.0f : 0.0f;
    }
}

// ---------- left-looking PW=16 panel Cholesky over `ncols` cols, `rows` rows ----------
// MODE 0: direct (all rows in LDS Lh).  MODE 1: split first half (rows>=256 -> G slab).
// MODE 2: split second half (source = S slab). Returns sum(log2(pivots)) on wave 0.
template <int MODE, int CT>
__device__ float chol_panels(char* arena, f16* __restrict__ G, float* __restrict__ S,
                             const float* __restrict__ L, const int* idx,
                             int k, int rows, int ncols, bool add1) {
    const int tid = threadIdx.x;
    const int lane = tid & 63, wv = tid >> 6;
    f16* Lh = (f16*)(arena + LH_OFF);
    float* P = (float*)(arena + P_OFF);
    f16* M = (f16*)(arena + M_OFF);
    const int frow = lane & 15, koff = (lane >> 4) * 8;
    const int crow = (lane >> 4) * 4, ccol = lane & 15;

    float lg2 = 0.0f;
    const int npan = ncols >> 4;
    for (int p = 0; p < npan; ++p) {
        const int jb = p << 4;
        const int ntile = (rows - jb) >> 4;

        // tile ownership: wave 0 -> diag only; wave w>=1 -> tiles w, w+15, ...
        int r0_[CT], baseA_[CT];
        bool val_[CT], isg_[CT];
#pragma unroll
        for (int it = 0; it < CT; ++it) {
            const int ti = (wv == 0) ? (it == 0 ? 0 : (1 << 20)) : (wv + 15 * it);
            const bool v = ti < ntile;
            const int r0 = jb + ((v ? ti : 0) << 4);
            r0_[it] = r0;
            val_[it] = v;
            const bool gg = (MODE == 1) && v && (r0 >= 256);
            isg_[it] = gg;
            baseA_[it] = gg ? ((r0 - 256 + frow) * 256 + koff)
                            : (lh_base(r0 + frow) + koff);
        }
        const int baseB = lh_base(jb + frow) + koff;

        // scattered gathers (issued early, consumed at P store)
        f32x4 g_[CT];
#pragma unroll
        for (int it = 0; it < CT; ++it)
            if (val_[it]) {
#pragma unroll
                for (int q = 0; q < 4; ++q)
                    g_[it][q] = gath<MODE>(L, S, idx, k, add1, r0_[it] + crow + q, jb + ccol);
            }

        // ---- (a) kk-chain, strip-mined 4 chunks per group (loads issued together)
        const int nkk = (jb + 31) >> 5;
        f32x4 acc_[CT];
#pragma unroll
        for (int it = 0; it < CT; ++it) acc_[it] = (f32x4){0.f, 0.f, 0.f, 0.f};

        for (int cg = 0; cg < nkk; cg += 4) {
            f16x8 A_[4][CT], B_[4];
#pragma unroll
            for (int u = 0; u < 4; ++u) {
                const int c = cg + u;
                const int kk = c << 5;
                const bool ok = (c < nkk) && (kk + koff < jb);
                B_[u] = ok ? *(const f16x8*)(&Lh[baseB + kk]) : (f16x8){};
#pragma unroll
                for (int it = 0; it < CT; ++it) {
                    f16x8 vv = {};
                    if (ok && val_[it]) {
                        if (MODE == 1 && isg_[it]) vv = *(const f16x8*)(&G[baseA_[it] + kk]);
                        else vv = *(const f16x8*)(&Lh[baseA_[it] + kk]);
                    }
                    A_[u][it] = vv;
                }
            }
#pragma unroll
            for (int u = 0; u < 4; ++u) {
                if (cg + u < nkk) {
#pragma unroll
                    for (int it = 0; it < CT; ++it)
                        if (val_[it])
                            acc_[it] = __builtin_amdgcn_mfma_f32_16x16x32_f16(
                                A_[u][it], B_[u], acc_[it], 0, 0, 0);
                }
            }
        }

        // P store (own rows) — LDS in-order per wave, same-wave re-read safe
#pragma unroll
        for (int it = 0; it < CT; ++it)
            if (val_[it]) {
                const int lr = r0_[it] - jb;
#pragma unroll
                for (int q = 0; q < 4; ++q)
                    P[(lr + crow + q) * 24 + ccol] = g_[it][q] - acc_[it][q];
            }

        // own (c) A-frags from own P rows (no barrier needed)
        f16x8 afs[CT];
#pragma unroll
        for (int it = 0; it < CT; ++it) {
            f16x8 af = {};
            if (val_[it] && wv != 0 && koff < 16) {
                const int lr = r0_[it] - jb;
                const f32x4 v0 = *(const f32x4*)(&P[(lr + frow) * 24 + koff]);
                const f32x4 v1 = *(const f32x4*)(&P[(lr + frow) * 24 + koff + 4]);
#pragma unroll
                for (int mq = 0; mq < 4; ++mq) {
                    af[mq] = (f16)v0[mq];
                    af[mq + 4] = (f16)v1[mq];
                }
            }
            afs[it] = af;
        }

        // ---- (b) wave 0: factor diag via column ops; inverse as by-product
        if (wv == 0) {
            const int r = lane & 15;
            float row[16], w[16];
#pragma unroll
            for (int q4 = 0; q4 < 4; ++q4) {
                const f32x4 t = *(const f32x4*)(&P[r * 24 + 4 * q4]);
#pragma unroll
                for (int m = 0; m < 4; ++m) row[4 * q4 + m] = t[m];
            }
#pragma unroll
            for (int c = 0; c < 16; ++c) w[c] = (c == r) ? 1.0f : 0.0f;
#pragma unroll
            for (int j = 0; j < 16; ++j) {
                const float piv = rdl(row[j], j);
                lg2 += __log2f(piv);
                const float irs = rsqrtf(piv);
                row[j] *= irs;
                w[j] *= irs;
#pragma unroll
                for (int cc = j + 1; cc < 16; ++cc) {
                    const float s = rdl(row[j], cc);   // L[cc][j], uniform
                    row[cc] = fmaf(-row[j], s, row[cc]);
                    w[cc] = fmaf(-s, w[j], w[cc]);
                }
            }
            if (lane < 16) {
                f16x8 hv0, hv1;
#pragma unroll
                for (int m = 0; m < 8; ++m) {
                    hv0[m] = (f16)row[m];
                    hv1[m] = (f16)row[8 + m];
                }
                *(f16x8*)(&Lh[lh_base(jb + lane) + jb]) = hv0;
                if (lane >= 8) *(f16x8*)(&Lh[lh_base(jb + lane) + jb + 8]) = hv1;
            }
            if (lane < 32) {
#pragma unroll
                for (int i = 0; i < 16; ++i)
                    M[i * 40 + lane] = (lane < 16) ? (f16)w[i] : (f16)0.0f;
            }
        }
        __syncthreads();            // barrier 1: M + diag factor rows visible

        // ---- (c) X = S_tile · M^T : one MFMA per owned tile
        const f16x8 bfM = *(const f16x8*)(&M[frow * 40 + koff]);
#pragma unroll
        for (int it = 0; it < CT; ++it) {
            if (val_[it] && wv != 0) {
                f32x4 xx = {0.f, 0.f, 0.f, 0.f};
                xx = __builtin_amdgcn_mfma_f32_16x16x32_f16(afs[it], bfM, xx, 0, 0, 0);
#pragma unroll
                for (int q = 0; q < 4; ++q) {
                    const int gr = r0_[it] + crow + q;
                    const f16 h = (f16)xx[q];
                    if (MODE == 1 && gr >= 256) G[(gr - 256) * 256 + jb + ccol] = h;
                    else Lh[lh_base(gr) + jb + ccol] = h;
                }
            }
        }
        __syncthreads();            // barrier 2: factor cols jb..jb+15 published
    }
    return lg2;
}

// ---------- S = A22 - G·G^T (split path), 16x16 tiles over lower triangle ----------
__device__ void schur_gemm(const f16* __restrict__ G, float* __restrict__ S,
                           const float* __restrict__ L, const int* idx,
                           int k, int k2p, bool add1) {
    const int tid = threadIdx.x;
    const int lane = tid & 63, wv = tid >> 6;
    const int frow = lane & 15, koff = (lane >> 4) * 8;
    const int crow = (lane >> 4) * 4, ccol = lane & 15;
    const int nt2 = k2p >> 4, TT = (nt2 * (nt2 + 1)) >> 1;
    for (int e = wv; e < TT; e += NW) {
        int R, C;
        tri_map(e, &R, &C);
        const int r0 = R << 4, c0 = C << 4;
        f32x4 g;
#pragma unroll
        for (int q = 0; q < 4; ++q) {
            const int gr = 256 + r0 + crow + q, gc = 256 + c0 + ccol;
            float v;
            if (gr < k && gc < k) {
                v = L[idx[gr] * N + idx[gc]];
                if (add1 && gr == gc) v += 1.0f;
            } else v = (gr == gc) ? 1.0f : 0.0f;
            g[q] = v;
        }
        const int ba = (r0 + frow) * 256 + koff, bb = (c0 + frow) * 256 + koff;
        f32x4 acc = {0.f, 0.f, 0.f, 0.f};
        for (int cg = 0; cg < 8; cg += 4) {
            f16x8 A_[4], B_[4];
#pragma unroll
            for (int u = 0; u < 4; ++u) {
                A_[u] = *(const f16x8*)(&G[ba + ((cg + u) << 5)]);
                B_[u] = *(const f16x8*)(&G[bb + ((cg + u) << 5)]);
            }
#pragma unroll
            for (int u = 0; u < 4; ++u)
                acc = __builtin_amdgcn_mfma_f32_16x16x32_f16(A_[u], B_[u], acc, 0, 0, 0);
        }
#pragma unroll
        for (int q = 0; q < 4; ++q)
            S[(r0 + crow + q) * SLD + c0 + ccol] = g[q] - acc[q];
    }
}

// ---------- one block per batch item; block BATCH = logdet(L+I) ----------
__global__ __launch_bounds__(TPB) void chol_all(const int* __restrict__ x,
                                                const float* __restrict__ L,
                                                char* __restrict__ slabs, int nslabs,
                                                float* __restrict__ logs) {
    const int b = blockIdx.x;
    const int tid = threadIdx.x;
    const int lane = tid & 63, wv = tid >> 6;
    __shared__ __align__(16) char arena[ARENA_SZ];
    __shared__ int idx[N];
    __shared__ int wcnt[NW];

    const bool zc = (b == BATCH);
    const bool inx = tid < N;
    const bool act = zc ? inx : (inx && x[(size_t)b * N + tid] != 0);
    const unsigned long long m = __ballot(act);
    if (lane == 0) wcnt[wv] = __popcll(m);
    __syncthreads();
    int off = 0, ktot = 0;
    for (int q = 0; q < NW; ++q) {
        if (q < wv) off += wcnt[q];
        ktot += wcnt[q];
    }
    if (act) idx[off + __popcll(m & ((1ULL << lane) - 1ULL))] = tid;
    __syncthreads();

    const int k = ktot;
    const int kp = (k + 15) & ~15;

    float lg2;
    if (!zc && kp <= KP) {
        lg2 = chol_panels<0, 2>(arena, nullptr, nullptr, L, idx, k, kp, kp, false);
    } else {
        const int si = zc ? 0 : (nslabs > 1 ? 1 + (b % (nslabs - 1)) : 0);
        char* slab = slabs + (size_t)si * SLAB_BYTES;
        f16* G = (f16*)slab;
        float* S = (float*)(slab + G_BYTES);
        const int k2 = k - 256, k2p = kp - 256;
        lg2 = chol_panels<1, 3>(arena, G, nullptr, L, idx, k, kp, 256, zc);
        schur_gemm(G, S, L, idx, k, k2p, zc);
        __syncthreads();
        lg2 += chol_panels<2, 1>(arena, nullptr, S, L, idx, k2, k2p, k2p, false);
    }
    if (tid == 0) logs[b] = lg2 * LN2;
}

__global__ void finalize(const float* __restrict__ logs, float* __restrict__ out) {
    const int i = threadIdx.x;
    out[i] = logs[i] - logs[BATCH];
}

extern "C" void kernel_launch(void* const* d_in, const int* in_sizes, int n_in,
                              void* d_out, int out_size, void* d_ws, size_t ws_size,
                              hipStream_t stream) {
    const int* x = (const int*)d_in[0];
    const float* B = (const float*)d_in[1];
    float* out = (float*)d_out;

    char* ws = (char*)d_ws;
    const size_t L_bytes = (size_t)N * N * 4;  // 1 MB
    float* L = (float*)ws;
    float* logs = (float*)(ws + L_bytes);
    const size_t head = L_bytes + 4096;
    char* slabs = ws + head;
    int nslabs = (ws_size > head) ? (int)((ws_size - head) / SLAB_BYTES) : 1;
    if (nslabs < 1) nslabs = 1;
    if (nslabs > 9) nslabs = 9;

    compute_L<<<dim3(8, 8), 256, 0, stream>>>(B, L);
    chol_all<<<BATCH + 1, TPB, 0, stream>>>(x, L, slabs, nslabs, logs);
    finalize<<<1, BATCH, 0, stream>>>(logs, out);
}

// Round 8
// 223.448 us; speedup vs baseline: 104.6991x; 1.0067x over previous
//
#include <hip/hip_runtime.h>
#include <math.h>

#define N 512
#define BATCH 128
#define EPS 1e-8f
#define TPB 1024         // 16 waves, 4/SIMD
#define NW 16
#define KP 304           // max kp for direct LDS path
#define LN2 0.69314718055994530942f
#define SLD 260          // S row stride (floats)

typedef _Float16 f16;
typedef _Float16 f16x8 __attribute__((ext_vector_type(8)));
typedef float f32x4 __attribute__((ext_vector_type(4)));

// packed fp16 triangle: row r starts 16B-aligned, length rup(r+1,8)
__device__ __forceinline__ int lh_base(int r) {
    const int a = r >> 3, b = r & 7;
    return 8 * (a + 1) * (4 * a + b);
}

// LDS arena (bytes): Lh fp16 triangle rows<=304 | P fp32 [512][24] | M fp16 [16][40]
#define LH_OFF 0
#define P_OFF  94848
#define M_OFF  144000
#define ARENA_SZ 145280

// global slab per split-block: G fp16 [256][256] | S fp32 [256][SLD]
#define G_BYTES 131072
#define S_BYTES (256 * SLD * 4)
#define SLAB_BYTES (G_BYTES + S_BYTES)

__device__ __forceinline__ float rdl(float v, int l) {
    return __builtin_bit_cast(float,
        __builtin_amdgcn_readlane(__builtin_bit_cast(int, v), l));
}

__device__ __forceinline__ void tri_map(int e, int* r_out, int* c_out) {
    int rr = (int)((sqrtf(8.0f * (float)e + 1.0f) - 1.0f) * 0.5f);
    while ((((rr + 1) * (rr + 2)) >> 1) <= e) ++rr;
    while (((rr * (rr + 1)) >> 1) > e) --rr;
    *r_out = rr;
    *c_out = e - ((rr * (rr + 1)) >> 1);
}

// ---------- L = B^T B + EPS*I : 64x64 register-tiled ----------
__global__ __launch_bounds__(256) void compute_L(const float* __restrict__ B,
                                                 float* __restrict__ L) {
    const int r0 = blockIdx.x * 64, c0 = blockIdx.y * 64;
    const int tx = threadIdx.x & 15, ty = threadIdx.x >> 4;
    __shared__ float Bi[16][64];
    __shared__ float Bj[16][64];
    float acc[4][4] = {};
    for (int k0 = 0; k0 < N; k0 += 16) {
#pragma unroll
        for (int q = 0; q < 4; ++q) {
            const int e = threadIdx.x + q * 256;
            const int kr = e >> 6, cc = e & 63;
            Bi[kr][cc] = B[(k0 + kr) * N + r0 + cc];
            Bj[kr][cc] = B[(k0 + kr) * N + c0 + cc];
        }
        __syncthreads();
#pragma unroll
        for (int kq = 0; kq < 16; ++kq) {
            float a[4], b[4];
#pragma unroll
            for (int q = 0; q < 4; ++q) {
                a[q] = Bi[kq][ty * 4 + q];
                b[q] = Bj[kq][tx * 4 + q];
            }
#pragma unroll
            for (int i = 0; i < 4; ++i)
#pragma unroll
                for (int j = 0; j < 4; ++j) acc[i][j] = fmaf(a[i], b[j], acc[i][j]);
        }
        __syncthreads();
    }
#pragma unroll
    for (int i = 0; i < 4; ++i) {
        const int r = r0 + ty * 4 + i;
        f32x4 v;
#pragma unroll
        for (int j = 0; j < 4; ++j) {
            const int c = c0 + tx * 4 + j;
            v[j] = acc[i][j] + ((r == c) ? EPS : 0.0f);
        }
        *(f32x4*)(&L[r * N + c0 + tx * 4]) = v;
    }
}

// gather one source entry. MODE 0/1: from L via idx (+add1 diag); MODE 2: from S (lower tri)
template <int MODE>
__device__ __forceinline__ float gath(const float* __restrict__ L,
                                      const float* __restrict__ S, const int* idx,
                                      int k, bool add1, int gr, int gc) {
    if constexpr (MODE <= 1) {
        if (gr < k && gc < k) {
            float v = L[idx[gr] * N + idx[gc]];
            if (add1 && gr == gc) v += 1.0f;
            return v;
        }
        return (gr == gc) ? 1.0f : 0.0f;
    } else {
        if (gr < k && gc < k) {
            const int r2 = gr > gc ? gr : gc, c2 = gr > gc ? gc : gr;
            return S[r2 * SLD + c2];
        }
        return (gr == gc) ? 1.0f : 0.0f;
    }
}

// ---------- left-looking PW=16 panel Cholesky over `ncols` cols, `rows` rows ----------
// MODE 0: direct (all rows in LDS Lh).  MODE 1: split first half (rows>=256 -> G slab).
// MODE 2: split second half (source = S slab). Returns sum(log2(pivots)) on wave 0.
template <int MODE, int CT>
__device__ float chol_panels(char* arena, f16* __restrict__ G, float* __restrict__ S,
                             const float* __restrict__ L, const int* idx,
                             int k, int rows, int ncols, bool add1) {
    const int tid = threadIdx.x;
    const int lane = tid & 63, wv = tid >> 6;
    f16* Lh = (f16*)(arena + LH_OFF);
    float* P = (float*)(arena + P_OFF);
    f16* M = (f16*)(arena + M_OFF);
    const int frow = lane & 15, koff = (lane >> 4) * 8;
    const int crow = (lane >> 4) * 4, ccol = lane & 15;

    float lg2 = 0.0f;
    const int npan = ncols >> 4;
    for (int p = 0; p < npan; ++p) {
        const int jb = p << 4;
        const int ntile = (rows - jb) >> 4;

        // tile ownership: wave 0 -> diag only; wave w>=1 -> tiles w, w+15, ...
        int r0_[CT], baseA_[CT];
        bool val_[CT], isg_[CT];
#pragma unroll
        for (int it = 0; it < CT; ++it) {
            const int ti = (wv == 0) ? (it == 0 ? 0 : (1 << 20)) : (wv + 15 * it);
            const bool v = ti < ntile;
            const int r0 = jb + ((v ? ti : 0) << 4);
            r0_[it] = r0;
            val_[it] = v;
            const bool gg = (MODE == 1) && v && (r0 >= 256);
            isg_[it] = gg;
            baseA_[it] = gg ? ((r0 - 256 + frow) * 256 + koff)
                            : (lh_base(r0 + frow) + koff);
        }
        const int baseB = lh_base(jb + frow) + koff;

        // scattered gathers (issued early, consumed at P store)
        f32x4 g_[CT];
#pragma unroll
        for (int it = 0; it < CT; ++it)
            if (val_[it]) {
#pragma unroll
                for (int q = 0; q < 4; ++q)
                    g_[it][q] = gath<MODE>(L, S, idx, k, add1, r0_[it] + crow + q, jb + ccol);
            }

        // ---- (a) kk-chain, strip-mined 4 chunks per group (loads issued together)
        const int nkk = (jb + 31) >> 5;
        f32x4 acc_[CT];
#pragma unroll
        for (int it = 0; it < CT; ++it) acc_[it] = (f32x4){0.f, 0.f, 0.f, 0.f};

        for (int cg = 0; cg < nkk; cg += 4) {
            f16x8 A_[4][CT], B_[4];
#pragma unroll
            for (int u = 0; u < 4; ++u) {
                const int c = cg + u;
                const int kk = c << 5;
                const bool ok = (c < nkk) && (kk + koff < jb);
                B_[u] = ok ? *(const f16x8*)(&Lh[baseB + kk]) : (f16x8){};
#pragma unroll
                for (int it = 0; it < CT; ++it) {
                    f16x8 vv = {};
                    if (ok && val_[it]) {
                        if (MODE == 1 && isg_[it]) vv = *(const f16x8*)(&G[baseA_[it] + kk]);
                        else vv = *(const f16x8*)(&Lh[baseA_[it] + kk]);
                    }
                    A_[u][it] = vv;
                }
            }
#pragma unroll
            for (int u = 0; u < 4; ++u) {
                if (cg + u < nkk) {
#pragma unroll
                    for (int it = 0; it < CT; ++it)
                        if (val_[it])
                            acc_[it] = __builtin_amdgcn_mfma_f32_16x16x32_f16(
                                A_[u][it], B_[u], acc_[it], 0, 0, 0);
                }
            }
        }

        // P store (own rows) — LDS in-order per wave, same-wave re-read safe
#pragma unroll
        for (int it = 0; it < CT; ++it)
            if (val_[it]) {
                const int lr = r0_[it] - jb;
#pragma unroll
                for (int q = 0; q < 4; ++q)
                    P[(lr + crow + q) * 24 + ccol] = g_[it][q] - acc_[it][q];
            }

        // own (c) A-frags from own P rows (no barrier needed)
        f16x8 afs[CT];
#pragma unroll
        for (int it = 0; it < CT; ++it) {
            f16x8 af = {};
            if (val_[it] && wv != 0 && koff < 16) {
                const int lr = r0_[it] - jb;
                const f32x4 v0 = *(const f32x4*)(&P[(lr + frow) * 24 + koff]);
                const f32x4 v1 = *(const f32x4*)(&P[(lr + frow) * 24 + koff + 4]);
#pragma unroll
                for (int mq = 0; mq < 4; ++mq) {
                    af[mq] = (f16)v0[mq];
                    af[mq + 4] = (f16)v1[mq];
                }
            }
            afs[it] = af;
        }

        // ---- (b) wave 0: factor diag via column ops; inverse as by-product
        if (wv == 0) {
            const int r = lane & 15;
            float row[16], w[16];
#pragma unroll
            for (int q4 = 0; q4 < 4; ++q4) {
                const f32x4 t = *(const f32x4*)(&P[r * 24 + 4 * q4]);
#pragma unroll
                for (int m = 0; m < 4; ++m) row[4 * q4 + m] = t[m];
            }
#pragma unroll
            for (int c = 0; c < 16; ++c) w[c] = (c == r) ? 1.0f : 0.0f;
#pragma unroll
            for (int j = 0; j < 16; ++j) {
                const float piv = rdl(row[j], j);
                lg2 += __log2f(piv);
                const float irs = rsqrtf(piv);
                row[j] *= irs;
                w[j] *= irs;
#pragma unroll
                for (int cc = j + 1; cc < 16; ++cc) {
                    const float s = rdl(row[j], cc);   // L[cc][j], uniform
                    row[cc] = fmaf(-row[j], s, row[cc]);
                    w[cc] = fmaf(-s, w[j], w[cc]);
                }
            }
            if (lane < 16) {
                f16x8 hv0, hv1;
#pragma unroll
                for (int m = 0; m < 8; ++m) {
                    hv0[m] = (f16)row[m];
                    hv1[m] = (f16)row[8 + m];
                }
                *(f16x8*)(&Lh[lh_base(jb + lane) + jb]) = hv0;
                if (lane >= 8) *(f16x8*)(&Lh[lh_base(jb + lane) + jb + 8]) = hv1;
            }
            if (lane < 32) {
#pragma unroll
                for (int i = 0; i < 16; ++i)
                    M[i * 40 + lane] = (lane < 16) ? (f16)w[i] : (f16)0.0f;
            }
        }
        __syncthreads();            // barrier 1: M + diag factor rows visible

        // ---- (c) X = S_tile · M^T : one MFMA per owned tile
        const f16x8 bfM = *(const f16x8*)(&M[frow * 40 + koff]);
#pragma unroll
        for (int it = 0; it < CT; ++it) {
            if (val_[it] && wv != 0) {
                f32x4 xx = {0.f, 0.f, 0.f, 0.f};
                xx = __builtin_amdgcn_mfma_f32_16x16x32_f16(afs[it], bfM, xx, 0, 0, 0);
#pragma unroll
                for (int q = 0; q < 4; ++q) {
                    const int gr = r0_[it] + crow + q;
                    const f16 h = (f16)xx[q];
                    if (MODE == 1 && gr >= 256) G[(gr - 256) * 256 + jb + ccol] = h;
                    else Lh[lh_base(gr) + jb + ccol] = h;
                }
            }
        }
        __syncthreads();            // barrier 2: factor cols jb..jb+15 published
    }
    return lg2;
}

// ---------- S = A22 - G·G^T (split path), 16x16 tiles over lower triangle ----------
__device__ void schur_gemm(const f16* __restrict__ G, float* __restrict__ S,
                           const float* __restrict__ L, const int* idx,
                           int k, int k2p, bool add1) {
    const int tid = threadIdx.x;
    const int lane = tid & 63, wv = tid >> 6;
    const int frow = lane & 15, koff = (lane >> 4) * 8;
    const int crow = (lane >> 4) * 4, ccol = lane & 15;
    const int nt2 = k2p >> 4, TT = (nt2 * (nt2 + 1)) >> 1;
    for (int e = wv; e < TT; e += NW) {
        int R, C;
        tri_map(e, &R, &C);
        const int r0 = R << 4, c0 = C << 4;
        f32x4 g;
#pragma unroll
        for (int q = 0; q < 4; ++q) {
            const int gr = 256 + r0 + crow + q, gc = 256 + c0 + ccol;
            float v;
            if (gr < k && gc < k) {
                v = L[idx[gr] * N + idx[gc]];
                if (add1 && gr == gc) v += 1.0f;
            } else v = (gr == gc) ? 1.0f : 0.0f;
            g[q] = v;
        }
        const int ba = (r0 + frow) * 256 + koff, bb = (c0 + frow) * 256 + koff;
        f32x4 acc = {0.f, 0.f, 0.f, 0.f};
        for (int cg = 0; cg < 8; cg += 4) {
            f16x8 A_[4], B_[4];
#pragma unroll
            for (int u = 0; u < 4; ++u) {
                A_[u] = *(const f16x8*)(&G[ba + ((cg + u) << 5)]);
                B_[u] = *(const f16x8*)(&G[bb + ((cg + u) << 5)]);
            }
#pragma unroll
            for (int u = 0; u < 4; ++u)
                acc = __builtin_amdgcn_mfma_f32_16x16x32_f16(A_[u], B_[u], acc, 0, 0, 0);
        }
#pragma unroll
        for (int q = 0; q < 4; ++q)
            S[(r0 + crow + q) * SLD + c0 + ccol] = g[q] - acc[q];
    }
}

// ---------- one block per batch item; block BATCH = logdet(L+I) ----------
__global__ __launch_bounds__(TPB) void chol_all(const int* __restrict__ x,
                                                const float* __restrict__ L,
                                                char* __restrict__ slabs, int nslabs,
                                                float* __restrict__ logs) {
    const int b = blockIdx.x;
    const int tid = threadIdx.x;
    const int lane = tid & 63, wv = tid >> 6;
    __shared__ __align__(16) char arena[ARENA_SZ];
    __shared__ int idx[N];
    __shared__ int wcnt[NW];

    const bool zc = (b == BATCH);
    const bool inx = tid < N;
    const bool act = zc ? inx : (inx && x[(size_t)b * N + tid] != 0);
    const unsigned long long m = __ballot(act);
    if (lane == 0) wcnt[wv] = __popcll(m);
    __syncthreads();
    int off = 0, ktot = 0;
    for (int q = 0; q < NW; ++q) {
        if (q < wv) off += wcnt[q];
        ktot += wcnt[q];
    }
    if (act) idx[off + __popcll(m & ((1ULL << lane) - 1ULL))] = tid;
    __syncthreads();

    const int k = ktot;
    const int kp = (k + 15) & ~15;

    float lg2;
    if (!zc && kp <= KP) {
        lg2 = chol_panels<0, 2>(arena, nullptr, nullptr, L, idx, k, kp, kp, false);
    } else {
        const int si = zc ? 0 : (nslabs > 1 ? 1 + (b % (nslabs - 1)) : 0);
        char* slab = slabs + (size_t)si * SLAB_BYTES;
        f16* G = (f16*)slab;
        float* S = (float*)(slab + G_BYTES);
        const int k2 = k - 256, k2p = kp - 256;
        lg2 = chol_panels<1, 3>(arena, G, nullptr, L, idx, k, kp, 256, zc);
        schur_gemm(G, S, L, idx, k, k2p, zc);
        __syncthreads();
        lg2 += chol_panels<2, 1>(arena, nullptr, S, L, idx, k2, k2p, k2p, false);
    }
    if (tid == 0) logs[b] = lg2 * LN2;
}

__global__ void finalize(const float* __restrict__ logs, float* __restrict__ out) {
    const int i = threadIdx.x;
    out[i] = logs[i] - logs[BATCH];
}

extern "C" void kernel_launch(void* const* d_in, const int* in_sizes, int n_in,
                              void* d_out, int out_size, void* d_ws, size_t ws_size,
                              hipStream_t stream) {
    const int* x = (const int*)d_in[0];
    const float* B = (const float*)d_in[1];
    float* out = (float*)d_out;

    char* ws = (char*)d_ws;
    const size_t L_bytes = (size_t)N * N * 4;  // 1 MB
    float* L = (float*)ws;
    float* logs = (float*)(ws + L_bytes);
    const size_t head = L_bytes + 4096;
    char* slabs = ws + head;
    int nslabs = (ws_size > head) ? (int)((ws_size - head) / SLAB_BYTES) : 1;
    if (nslabs < 1) nslabs = 1;
    if (nslabs > 9) nslabs = 9;

    compute_L<<<dim3(8, 8), 256, 0, stream>>>(B, L);
    chol_all<<<BATCH + 1, TPB, 0, stream>>>(x, L, slabs, nslabs, logs);
    finalize<<<1, BATCH, 0, stream>>>(logs, out);
}